// Round 1
// baseline (6999.001 us; speedup 1.0000x reference)
//
#include <hip/hip_runtime.h>
#include <hip/hip_bf16.h>
#include <math.h>

#define BB 2
#define LL 1024
#define DIM 512
#define NL 6
#define DI 1024
#define DS 16
#define DC 4
#define DR 32
#define VOCAB 32000
#define M_ROWS (BB * LL)   // 2048

// ---------------------------------------------------------------------------
// embed + pos
// ---------------------------------------------------------------------------
__global__ __launch_bounds__(256) void embed_kernel(const int* __restrict__ tok,
                                                    const float* __restrict__ pos,
                                                    const float* __restrict__ emb,
                                                    float* __restrict__ x) {
    int idx = blockIdx.x * 256 + threadIdx.x;           // B*L*DIM = 1048576
    int d = idx & (DIM - 1);
    int l = (idx >> 9) & (LL - 1);
    int b = idx >> 19;
    int t = tok[b * LL + l];
    x[idx] = emb[(size_t)t * DIM + d] + pos[l * DIM + d];
}

// ---------------------------------------------------------------------------
// Tiled fp32 GEMM:  C[M,N] = A[M,K] * W[N,K]^T  (+ optional bias[N])
// BM=BN=64, BK=16, 256 threads, 4x4 micro-tile
// ---------------------------------------------------------------------------
#define BM 64
#define BN 64
#define BK 16
__global__ __launch_bounds__(256) void gemm_nt(const float* __restrict__ A,
                                               const float* __restrict__ W,
                                               const float* __restrict__ bias,
                                               float* __restrict__ C,
                                               int M, int N, int K) {
    __shared__ float As[BK][BM];
    __shared__ float Ws[BK][BN];
    const int t = threadIdx.x;
    const int bm = blockIdx.y * BM;
    const int bn = blockIdx.x * BN;
    const int tx = t & 15;        // N micro dir
    const int ty = t >> 4;        // M micro dir
    const int row = t >> 2;       // staging: 0..63
    const int quad = t & 3;       // staging: 0..3

    float acc[4][4] = {};

    const float* Ap = A + (size_t)(bm + row) * K + quad * 4;
    const float* Wp = W + (size_t)(bn + row) * K + quad * 4;

    for (int k0 = 0; k0 < K; k0 += BK) {
        float4 av = *(const float4*)(Ap + k0);
        float4 wv = *(const float4*)(Wp + k0);
        __syncthreads();
        As[quad * 4 + 0][row] = av.x;
        As[quad * 4 + 1][row] = av.y;
        As[quad * 4 + 2][row] = av.z;
        As[quad * 4 + 3][row] = av.w;
        Ws[quad * 4 + 0][row] = wv.x;
        Ws[quad * 4 + 1][row] = wv.y;
        Ws[quad * 4 + 2][row] = wv.z;
        Ws[quad * 4 + 3][row] = wv.w;
        __syncthreads();
#pragma unroll
        for (int k = 0; k < BK; ++k) {
            float4 a = *(const float4*)&As[k][ty * 4];
            float4 w = *(const float4*)&Ws[k][tx * 4];
            acc[0][0] += a.x * w.x; acc[0][1] += a.x * w.y; acc[0][2] += a.x * w.z; acc[0][3] += a.x * w.w;
            acc[1][0] += a.y * w.x; acc[1][1] += a.y * w.y; acc[1][2] += a.y * w.z; acc[1][3] += a.y * w.w;
            acc[2][0] += a.z * w.x; acc[2][1] += a.z * w.y; acc[2][2] += a.z * w.z; acc[2][3] += a.z * w.w;
            acc[3][0] += a.w * w.x; acc[3][1] += a.w * w.y; acc[3][2] += a.w * w.z; acc[3][3] += a.w * w.w;
        }
    }

    float bv[4] = {0.f, 0.f, 0.f, 0.f};
    if (bias != nullptr) {
        float4 b4 = *(const float4*)(bias + bn + tx * 4);
        bv[0] = b4.x; bv[1] = b4.y; bv[2] = b4.z; bv[3] = b4.w;
    }
#pragma unroll
    for (int i = 0; i < 4; ++i) {
        float4 o;
        o.x = acc[i][0] + bv[0];
        o.y = acc[i][1] + bv[1];
        o.z = acc[i][2] + bv[2];
        o.w = acc[i][3] + bv[3];
        *(float4*)(C + (size_t)(bm + ty * 4 + i) * N + bn + tx * 4) = o;
    }
}

// ---------------------------------------------------------------------------
// causal depthwise conv (DC=4) + SiLU.  input = xz[:, :, :DI]
// ---------------------------------------------------------------------------
__global__ __launch_bounds__(256) void conv_silu(const float* __restrict__ xz,
                                                 const float* __restrict__ cw,
                                                 const float* __restrict__ cb,
                                                 float* __restrict__ xc) {
    int idx = blockIdx.x * 256 + threadIdx.x;   // B*L*DI = 2097152
    int c = idx & (DI - 1);
    int l = (idx >> 10) & (LL - 1);
    int b = idx >> 20;
    float acc = cb[c];
#pragma unroll
    for (int k = 0; k < DC; ++k) {
        int ll = l + k - (DC - 1);
        if (ll >= 0)
            acc += cw[c * DC + k] * xz[((size_t)(b * LL + ll)) * (2 * DI) + c];
    }
    xc[idx] = acc / (1.f + __expf(-acc));
}

// ---------------------------------------------------------------------------
// dt = softplus(xdbl[:, :DR] @ dtw^T + dtb)     (K=32)
// ---------------------------------------------------------------------------
__global__ __launch_bounds__(256) void dtproj(const float* __restrict__ xdbl,
                                              const float* __restrict__ dtw,
                                              const float* __restrict__ dtb,
                                              float* __restrict__ dt) {
    __shared__ float xd[DR];
    int m = blockIdx.y;
    int t = threadIdx.x;
    if (t < DR) xd[t] = xdbl[(size_t)m * 64 + t];
    __syncthreads();
    int d = blockIdx.x * 256 + t;
    float acc = dtb[d];
    const float4* w4 = (const float4*)(dtw + (size_t)d * DR);
#pragma unroll
    for (int q = 0; q < DR / 4; ++q) {
        float4 w = w4[q];
        acc += w.x * xd[q * 4 + 0] + w.y * xd[q * 4 + 1] +
               w.z * xd[q * 4 + 2] + w.w * xd[q * 4 + 3];
    }
    float sp = (acc > 20.f) ? acc : log1pf(__expf(acc));
    dt[(size_t)m * DI + d] = sp;
}

// ---------------------------------------------------------------------------
// selective scan + gating.  One thread per (b, d, n); 16-lane reduce over n.
// grid = B * DI/16 = 128 blocks, 256 threads (16 channels x 16 states)
// ---------------------------------------------------------------------------
__global__ __launch_bounds__(256) void scan_kernel(const float* __restrict__ xc,
                                                   const float* __restrict__ dt,
                                                   const float* __restrict__ xdbl,
                                                   const float* __restrict__ xz,
                                                   const float* __restrict__ A_log,
                                                   const float* __restrict__ Dpp,
                                                   float* __restrict__ y) {
    int bk = blockIdx.x;
    int b = bk >> 6;
    int d0 = (bk & 63) << 4;
    int t = threadIdx.x;
    int n = t & 15;
    int ch = t >> 4;
    int d = d0 + ch;

    float a = -__expf(A_log[d * DS + n]);
    float dp = Dpp[d];
    float h = 0.f;

    const float* dtp = dt + (size_t)b * LL * DI + d;
    const float* up  = xc + (size_t)b * LL * DI + d;
    const float* xdp = xdbl + (size_t)b * LL * 64;
    const float* zp  = xz + (size_t)b * LL * (2 * DI) + DI + d;
    float* yp = y + (size_t)b * LL * DI + d;

    for (int l = 0; l < LL; ++l) {
        float dtv = dtp[(size_t)l * DI];
        float uv  = up[(size_t)l * DI];
        float Bv  = xdp[l * 64 + DR + n];
        float Cv  = xdp[l * 64 + DR + DS + n];
        float dA = __expf(dtv * a);
        h = dA * h + dtv * Bv * uv;
        float p = h * Cv;
        p += __shfl_xor(p, 1, 16);
        p += __shfl_xor(p, 2, 16);
        p += __shfl_xor(p, 4, 16);
        p += __shfl_xor(p, 8, 16);
        if (n == 0) {
            float zv = zp[(size_t)l * (2 * DI)];
            float g = zv / (1.f + __expf(-zv));
            yp[(size_t)l * DI] = (p + uv * dp) * g;
        }
    }
}

// ---------------------------------------------------------------------------
// x = LayerNorm(x + o) * g + b        (row = 512, 256 threads x 2 elems)
// ---------------------------------------------------------------------------
__global__ __launch_bounds__(256) void add_ln(const float* __restrict__ o,
                                              float* __restrict__ x,
                                              const float* __restrict__ g,
                                              const float* __restrict__ b) {
    int m = blockIdx.x;
    int t = threadIdx.x;
    const float* xr = x + (size_t)m * DIM;
    const float* orr = o + (size_t)m * DIM;
    float v0 = xr[t] + orr[t];
    float v1 = xr[t + 256] + orr[t + 256];
    float s = v0 + v1;
    float ss = v0 * v0 + v1 * v1;
#pragma unroll
    for (int off = 32; off > 0; off >>= 1) {
        s += __shfl_down(s, off, 64);
        ss += __shfl_down(ss, off, 64);
    }
    __shared__ float sb[4], ssb[4];
    int w = t >> 6;
    if ((t & 63) == 0) { sb[w] = s; ssb[w] = ss; }
    __syncthreads();
    float stot = sb[0] + sb[1] + sb[2] + sb[3];
    float sstot = ssb[0] + ssb[1] + ssb[2] + ssb[3];
    float mean = stot * (1.f / DIM);
    float var = sstot * (1.f / DIM) - mean * mean;
    float rs = rsqrtf(var + 1e-5f);
    float* xw = x + (size_t)m * DIM;
    xw[t] = (v0 - mean) * rs * g[t] + b[t];
    xw[t + 256] = (v1 - mean) * rs * g[t + 256] + b[t + 256];
}

// ---------------------------------------------------------------------------
extern "C" void kernel_launch(void* const* d_in, const int* in_sizes, int n_in,
                              void* d_out, int out_size, void* d_ws, size_t ws_size,
                              hipStream_t stream) {
    const int*   tokens = (const int*)d_in[0];
    const float* pos    = (const float*)d_in[1];
    const float* emb    = (const float*)d_in[2];
    const float* lm_w   = (const float*)d_in[3];
    const float* lm_b   = (const float*)d_in[4];
    const float* in_w   = (const float*)d_in[5];
    const float* cw     = (const float*)d_in[6];
    const float* cb     = (const float*)d_in[7];
    const float* xpw    = (const float*)d_in[8];
    const float* dtw    = (const float*)d_in[9];
    const float* dtb    = (const float*)d_in[10];
    const float* A_log  = (const float*)d_in[11];
    const float* Dpp    = (const float*)d_in[12];
    const float* ow     = (const float*)d_in[13];
    const float* lng    = (const float*)d_in[14];
    const float* lnb    = (const float*)d_in[15];
    float* out = (float*)d_out;

    float* ws = (float*)d_ws;
    float* x    = ws;                   // 2048*512   = 1048576
    float* xz   = x + 1048576;          // 2048*2048  = 4194304
    float* xc   = xz + 4194304;         // 2048*1024  = 2097152
    float* xd   = xc + 2097152;         // 2048*64    = 131072
    float* dt   = xd + 131072;          // 2048*1024  = 2097152
    float* y    = dt + 2097152;         // 2048*1024  = 2097152
    float* o    = y + 2097152;          // 2048*512   = 1048576

    embed_kernel<<<M_ROWS * DIM / 256, 256, 0, stream>>>(tokens, pos, emb, x);

    for (int i = 0; i < NL; ++i) {
        gemm_nt<<<dim3((2 * DI) / BN, M_ROWS / BM), 256, 0, stream>>>(
            x, in_w + (size_t)i * (2 * DI) * DIM, nullptr, xz, M_ROWS, 2 * DI, DIM);
        conv_silu<<<M_ROWS * DI / 256, 256, 0, stream>>>(
            xz, cw + (size_t)i * DI * DC, cb + (size_t)i * DI, xc);
        gemm_nt<<<dim3(64 / BN, M_ROWS / BM), 256, 0, stream>>>(
            xc, xpw + (size_t)i * 64 * DI, nullptr, xd, M_ROWS, 64, DI);
        dtproj<<<dim3(DI / 256, M_ROWS), 256, 0, stream>>>(
            xd, dtw + (size_t)i * DI * DR, dtb + (size_t)i * DI, dt);
        scan_kernel<<<BB * DI / 16, 256, 0, stream>>>(
            xc, dt, xd, xz, A_log + (size_t)i * DI * DS, Dpp + (size_t)i * DI, y);
        gemm_nt<<<dim3(DIM / BN, M_ROWS / BM), 256, 0, stream>>>(
            y, ow + (size_t)i * DIM * DI, nullptr, o, M_ROWS, DIM, DI);
        add_ln<<<M_ROWS, 256, 0, stream>>>(
            o, x, lng + (size_t)i * DIM, lnb + (size_t)i * DIM);
    }

    gemm_nt<<<dim3(VOCAB / BN, M_ROWS / BM), 256, 0, stream>>>(
        x, lm_w, lm_b, out, M_ROWS, VOCAB, DIM);
}

// Round 2
// 2944.311 us; speedup vs baseline: 2.3771x; 2.3771x over previous
//
#include <hip/hip_runtime.h>
#include <hip/hip_bf16.h>
#include <math.h>

#define BB 2
#define LL 1024
#define DIM 512
#define NL 6
#define DI 1024
#define DS 16
#define DC 4
#define DR 32
#define VOCAB 32000
#define M_ROWS (BB * LL)   // 2048
#define CCH 32             // scan chunks
#define CHLEN (LL / CCH)   // 32

// ---------------------------------------------------------------------------
// embed + pos
// ---------------------------------------------------------------------------
__global__ __launch_bounds__(256) void embed_kernel(const int* __restrict__ tok,
                                                    const float* __restrict__ pos,
                                                    const float* __restrict__ emb,
                                                    float* __restrict__ x) {
    int idx = blockIdx.x * 256 + threadIdx.x;           // B*L*DIM = 1048576
    int d = idx & (DIM - 1);
    int l = (idx >> 9) & (LL - 1);
    int b = idx >> 19;
    int t = tok[b * LL + l];
    x[idx] = emb[(size_t)t * DIM + d] + pos[l * DIM + d];
}

// ---------------------------------------------------------------------------
// Tiled fp32 GEMM:  C[M,N] = A[M,K] * W[N,K]^T  (+ optional bias[N])
// ---------------------------------------------------------------------------
#define BM 64
#define BN 64
#define BK 16
__global__ __launch_bounds__(256) void gemm_nt(const float* __restrict__ A,
                                               const float* __restrict__ W,
                                               const float* __restrict__ bias,
                                               float* __restrict__ C,
                                               int M, int N, int K) {
    __shared__ float As[BK][BM];
    __shared__ float Ws[BK][BN];
    const int t = threadIdx.x;
    const int bm = blockIdx.y * BM;
    const int bn = blockIdx.x * BN;
    const int tx = t & 15;
    const int ty = t >> 4;
    const int row = t >> 2;
    const int quad = t & 3;

    float acc[4][4] = {};

    const float* Ap = A + (size_t)(bm + row) * K + quad * 4;
    const float* Wp = W + (size_t)(bn + row) * K + quad * 4;

    for (int k0 = 0; k0 < K; k0 += BK) {
        float4 av = *(const float4*)(Ap + k0);
        float4 wv = *(const float4*)(Wp + k0);
        __syncthreads();
        As[quad * 4 + 0][row] = av.x;
        As[quad * 4 + 1][row] = av.y;
        As[quad * 4 + 2][row] = av.z;
        As[quad * 4 + 3][row] = av.w;
        Ws[quad * 4 + 0][row] = wv.x;
        Ws[quad * 4 + 1][row] = wv.y;
        Ws[quad * 4 + 2][row] = wv.z;
        Ws[quad * 4 + 3][row] = wv.w;
        __syncthreads();
#pragma unroll
        for (int k = 0; k < BK; ++k) {
            float4 a = *(const float4*)&As[k][ty * 4];
            float4 w = *(const float4*)&Ws[k][tx * 4];
            acc[0][0] += a.x * w.x; acc[0][1] += a.x * w.y; acc[0][2] += a.x * w.z; acc[0][3] += a.x * w.w;
            acc[1][0] += a.y * w.x; acc[1][1] += a.y * w.y; acc[1][2] += a.y * w.z; acc[1][3] += a.y * w.w;
            acc[2][0] += a.z * w.x; acc[2][1] += a.z * w.y; acc[2][2] += a.z * w.z; acc[2][3] += a.z * w.w;
            acc[3][0] += a.w * w.x; acc[3][1] += a.w * w.y; acc[3][2] += a.w * w.z; acc[3][3] += a.w * w.w;
        }
    }

    float bv[4] = {0.f, 0.f, 0.f, 0.f};
    if (bias != nullptr) {
        float4 b4 = *(const float4*)(bias + bn + tx * 4);
        bv[0] = b4.x; bv[1] = b4.y; bv[2] = b4.z; bv[3] = b4.w;
    }
#pragma unroll
    for (int i = 0; i < 4; ++i) {
        float4 o;
        o.x = acc[i][0] + bv[0];
        o.y = acc[i][1] + bv[1];
        o.z = acc[i][2] + bv[2];
        o.w = acc[i][3] + bv[3];
        *(float4*)(C + (size_t)(bm + ty * 4 + i) * N + bn + tx * 4) = o;
    }
}

// ---------------------------------------------------------------------------
// causal depthwise conv (DC=4) + SiLU
// ---------------------------------------------------------------------------
__global__ __launch_bounds__(256) void conv_silu(const float* __restrict__ xz,
                                                 const float* __restrict__ cw,
                                                 const float* __restrict__ cb,
                                                 float* __restrict__ xc) {
    int idx = blockIdx.x * 256 + threadIdx.x;   // B*L*DI
    int c = idx & (DI - 1);
    int l = (idx >> 10) & (LL - 1);
    int b = idx >> 20;
    float acc = cb[c];
#pragma unroll
    for (int k = 0; k < DC; ++k) {
        int ll = l + k - (DC - 1);
        if (ll >= 0)
            acc += cw[c * DC + k] * xz[((size_t)(b * LL + ll)) * (2 * DI) + c];
    }
    xc[idx] = acc / (1.f + __expf(-acc));
}

// ---------------------------------------------------------------------------
// dt = softplus(xdbl[:, :DR] @ dtw^T + dtb)
// ---------------------------------------------------------------------------
__global__ __launch_bounds__(256) void dtproj(const float* __restrict__ xdbl,
                                              const float* __restrict__ dtw,
                                              const float* __restrict__ dtb,
                                              float* __restrict__ dt) {
    __shared__ float xd[DR];
    int m = blockIdx.y;
    int t = threadIdx.x;
    if (t < DR) xd[t] = xdbl[(size_t)m * 64 + t];
    __syncthreads();
    int d = blockIdx.x * 256 + t;
    float acc = dtb[d];
    const float4* w4 = (const float4*)(dtw + (size_t)d * DR);
#pragma unroll
    for (int q = 0; q < DR / 4; ++q) {
        float4 w = w4[q];
        acc += w.x * xd[q * 4 + 0] + w.y * xd[q * 4 + 1] +
               w.z * xd[q * 4 + 2] + w.w * xd[q * 4 + 3];
    }
    float sp = (acc > 20.f) ? acc : log1pf(__expf(acc));
    dt[(size_t)m * DI + d] = sp;
}

// ---------------------------------------------------------------------------
// Chunked selective scan.
// Pass 1: per (b,d,chunk) compute S = sum(dt) and Q = accumulated input
//         (h_out = exp(a*S)*h_in + Q).  16 states in registers.
// ---------------------------------------------------------------------------
__global__ __launch_bounds__(256) void scan_pass1(const float* __restrict__ xc,
                                                  const float* __restrict__ dt,
                                                  const float* __restrict__ xdbl,
                                                  const float* __restrict__ A_log,
                                                  float* __restrict__ S,
                                                  float* __restrict__ Q) {
    const int d = blockIdx.x * 256 + threadIdx.x;
    const int b = blockIdx.y;
    const int c = blockIdx.z;
    float a[DS];
#pragma unroll
    for (int q = 0; q < 4; ++q) {
        float4 al = *(const float4*)(A_log + d * DS + q * 4);
        a[q * 4 + 0] = -__expf(al.x);
        a[q * 4 + 1] = -__expf(al.y);
        a[q * 4 + 2] = -__expf(al.z);
        a[q * 4 + 3] = -__expf(al.w);
    }
    float Qr[DS];
#pragma unroll
    for (int n = 0; n < DS; ++n) Qr[n] = 0.f;
    float Ssum = 0.f;

    const int l0 = c * CHLEN;
    const float* dtp = dt + ((size_t)b * LL + l0) * DI + d;
    const float* up  = xc + ((size_t)b * LL + l0) * DI + d;
    const float* xdp = xdbl + ((size_t)b * LL + l0) * 64 + DR;

    for (int l = 0; l < CHLEN; ++l) {
        float dtv = dtp[(size_t)l * DI];
        float uv  = up[(size_t)l * DI];
        float w = dtv * uv;
        Ssum += dtv;
#pragma unroll
        for (int q = 0; q < 4; ++q) {
            float4 Bv = *(const float4*)(xdp + l * 64 + q * 4);
            float dA0 = __expf(dtv * a[q * 4 + 0]);
            float dA1 = __expf(dtv * a[q * 4 + 1]);
            float dA2 = __expf(dtv * a[q * 4 + 2]);
            float dA3 = __expf(dtv * a[q * 4 + 3]);
            Qr[q * 4 + 0] = dA0 * Qr[q * 4 + 0] + w * Bv.x;
            Qr[q * 4 + 1] = dA1 * Qr[q * 4 + 1] + w * Bv.y;
            Qr[q * 4 + 2] = dA2 * Qr[q * 4 + 2] + w * Bv.z;
            Qr[q * 4 + 3] = dA3 * Qr[q * 4 + 3] + w * Bv.w;
        }
    }
    S[((size_t)b * CCH + c) * DI + d] = Ssum;
    float* Qp = Q + (((size_t)b * CCH + c) * DI + d) * DS;
#pragma unroll
    for (int q = 0; q < 4; ++q) {
        float4 o;
        o.x = Qr[q * 4 + 0]; o.y = Qr[q * 4 + 1];
        o.z = Qr[q * 4 + 2]; o.w = Qr[q * 4 + 3];
        *(float4*)(Qp + q * 4) = o;
    }
}

// ---------------------------------------------------------------------------
// Pass 2: sequential combine over chunks; rewrite Q[c] with chunk START state.
// Thread per (b,d,n) = 32768 threads.
// ---------------------------------------------------------------------------
__global__ __launch_bounds__(256) void scan_pass2(const float* __restrict__ A_log,
                                                  const float* __restrict__ S,
                                                  float* __restrict__ Q) {
    const int idx = blockIdx.x * 256 + threadIdx.x;
    const int b = idx >> 14;          // DI*DS = 16384
    const int dn = idx & 16383;
    const int d = dn >> 4;
    const float a = -__expf(A_log[dn]);
    float h = 0.f;
    for (int c = 0; c < CCH; ++c) {
        const size_t soff = ((size_t)b * CCH + c) * DI + d;
        const size_t qoff = ((size_t)b * CCH + c) * (size_t)(DI * DS) + dn;
        float P = __expf(a * S[soff]);
        float q = Q[qoff];
        Q[qoff] = h;                  // start state for chunk c
        h = P * h + q;
    }
}

// ---------------------------------------------------------------------------
// Pass 3: re-run recurrence per chunk from start state, produce gated y.
// ---------------------------------------------------------------------------
__global__ __launch_bounds__(256) void scan_pass3(const float* __restrict__ xc,
                                                  const float* __restrict__ dt,
                                                  const float* __restrict__ xdbl,
                                                  const float* __restrict__ xz,
                                                  const float* __restrict__ A_log,
                                                  const float* __restrict__ Dpp,
                                                  const float* __restrict__ Q,
                                                  float* __restrict__ y) {
    const int d = blockIdx.x * 256 + threadIdx.x;
    const int b = blockIdx.y;
    const int c = blockIdx.z;
    float a[DS];
#pragma unroll
    for (int q = 0; q < 4; ++q) {
        float4 al = *(const float4*)(A_log + d * DS + q * 4);
        a[q * 4 + 0] = -__expf(al.x);
        a[q * 4 + 1] = -__expf(al.y);
        a[q * 4 + 2] = -__expf(al.z);
        a[q * 4 + 3] = -__expf(al.w);
    }
    float h[DS];
    const float* Qp = Q + (((size_t)b * CCH + c) * DI + d) * DS;
#pragma unroll
    for (int q = 0; q < 4; ++q) {
        float4 hv = *(const float4*)(Qp + q * 4);
        h[q * 4 + 0] = hv.x; h[q * 4 + 1] = hv.y;
        h[q * 4 + 2] = hv.z; h[q * 4 + 3] = hv.w;
    }
    const float dp = Dpp[d];

    const int l0 = c * CHLEN;
    const float* dtp = dt + ((size_t)b * LL + l0) * DI + d;
    const float* up  = xc + ((size_t)b * LL + l0) * DI + d;
    const float* xdp = xdbl + ((size_t)b * LL + l0) * 64 + DR;
    const float* zp  = xz + ((size_t)b * LL + l0) * (2 * DI) + DI + d;
    float* yp = y + ((size_t)b * LL + l0) * DI + d;

    for (int l = 0; l < CHLEN; ++l) {
        float dtv = dtp[(size_t)l * DI];
        float uv  = up[(size_t)l * DI];
        float w = dtv * uv;
        float p = 0.f;
#pragma unroll
        for (int q = 0; q < 4; ++q) {
            float4 Bv = *(const float4*)(xdp + l * 64 + q * 4);
            float4 Cv = *(const float4*)(xdp + l * 64 + 16 + q * 4);
            float dA0 = __expf(dtv * a[q * 4 + 0]);
            float dA1 = __expf(dtv * a[q * 4 + 1]);
            float dA2 = __expf(dtv * a[q * 4 + 2]);
            float dA3 = __expf(dtv * a[q * 4 + 3]);
            h[q * 4 + 0] = dA0 * h[q * 4 + 0] + w * Bv.x;
            h[q * 4 + 1] = dA1 * h[q * 4 + 1] + w * Bv.y;
            h[q * 4 + 2] = dA2 * h[q * 4 + 2] + w * Bv.z;
            h[q * 4 + 3] = dA3 * h[q * 4 + 3] + w * Bv.w;
            p += h[q * 4 + 0] * Cv.x + h[q * 4 + 1] * Cv.y +
                 h[q * 4 + 2] * Cv.z + h[q * 4 + 3] * Cv.w;
        }
        float zv = zp[(size_t)l * (2 * DI)];
        float g = zv / (1.f + __expf(-zv));
        yp[(size_t)l * DI] = (p + uv * dp) * g;
    }
}

// ---------------------------------------------------------------------------
// x = LayerNorm(x + o) * g + b
// ---------------------------------------------------------------------------
__global__ __launch_bounds__(256) void add_ln(const float* __restrict__ o,
                                              float* __restrict__ x,
                                              const float* __restrict__ g,
                                              const float* __restrict__ b) {
    int m = blockIdx.x;
    int t = threadIdx.x;
    const float* xr = x + (size_t)m * DIM;
    const float* orr = o + (size_t)m * DIM;
    float v0 = xr[t] + orr[t];
    float v1 = xr[t + 256] + orr[t + 256];
    float s = v0 + v1;
    float ss = v0 * v0 + v1 * v1;
#pragma unroll
    for (int off = 32; off > 0; off >>= 1) {
        s += __shfl_down(s, off, 64);
        ss += __shfl_down(ss, off, 64);
    }
    __shared__ float sb[4], ssb[4];
    int w = t >> 6;
    if ((t & 63) == 0) { sb[w] = s; ssb[w] = ss; }
    __syncthreads();
    float stot = sb[0] + sb[1] + sb[2] + sb[3];
    float sstot = ssb[0] + ssb[1] + ssb[2] + ssb[3];
    float mean = stot * (1.f / DIM);
    float var = sstot * (1.f / DIM) - mean * mean;
    float rs = rsqrtf(var + 1e-5f);
    float* xw = x + (size_t)m * DIM;
    xw[t] = (v0 - mean) * rs * g[t] + b[t];
    xw[t + 256] = (v1 - mean) * rs * g[t + 256] + b[t + 256];
}

// ---------------------------------------------------------------------------
extern "C" void kernel_launch(void* const* d_in, const int* in_sizes, int n_in,
                              void* d_out, int out_size, void* d_ws, size_t ws_size,
                              hipStream_t stream) {
    const int*   tokens = (const int*)d_in[0];
    const float* pos    = (const float*)d_in[1];
    const float* emb    = (const float*)d_in[2];
    const float* lm_w   = (const float*)d_in[3];
    const float* lm_b   = (const float*)d_in[4];
    const float* in_w   = (const float*)d_in[5];
    const float* cw     = (const float*)d_in[6];
    const float* cb     = (const float*)d_in[7];
    const float* xpw    = (const float*)d_in[8];
    const float* dtw    = (const float*)d_in[9];
    const float* dtb    = (const float*)d_in[10];
    const float* A_log  = (const float*)d_in[11];
    const float* Dpp    = (const float*)d_in[12];
    const float* ow     = (const float*)d_in[13];
    const float* lng    = (const float*)d_in[14];
    const float* lnb    = (const float*)d_in[15];
    float* out = (float*)d_out;

    float* ws = (float*)d_ws;
    float* x    = ws;                   // 1048576
    float* xz   = x + 1048576;          // 4194304
    float* xc   = xz + 4194304;         // 2097152
    float* xd   = xc + 2097152;         // 131072
    float* dt   = xd + 131072;          // 2097152
    float* y    = dt + 2097152;         // 2097152
    float* o    = y + 2097152;          // 1048576
    float* S    = o + 1048576;          // B*CCH*DI = 65536
    float* Qb   = S + 65536;            // B*CCH*DI*DS = 1048576

    embed_kernel<<<M_ROWS * DIM / 256, 256, 0, stream>>>(tokens, pos, emb, x);

    for (int i = 0; i < NL; ++i) {
        gemm_nt<<<dim3((2 * DI) / BN, M_ROWS / BM), 256, 0, stream>>>(
            x, in_w + (size_t)i * (2 * DI) * DIM, nullptr, xz, M_ROWS, 2 * DI, DIM);
        conv_silu<<<M_ROWS * DI / 256, 256, 0, stream>>>(
            xz, cw + (size_t)i * DI * DC, cb + (size_t)i * DI, xc);
        gemm_nt<<<dim3(64 / BN, M_ROWS / BM), 256, 0, stream>>>(
            xc, xpw + (size_t)i * 64 * DI, nullptr, xd, M_ROWS, 64, DI);
        dtproj<<<dim3(DI / 256, M_ROWS), 256, 0, stream>>>(
            xd, dtw + (size_t)i * DI * DR, dtb + (size_t)i * DI, dt);
        scan_pass1<<<dim3(DI / 256, BB, CCH), 256, 0, stream>>>(
            xc, dt, xd, A_log + (size_t)i * DI * DS, S, Qb);
        scan_pass2<<<(BB * DI * DS) / 256, 256, 0, stream>>>(
            A_log + (size_t)i * DI * DS, S, Qb);
        scan_pass3<<<dim3(DI / 256, BB, CCH), 256, 0, stream>>>(
            xc, dt, xd, xz, A_log + (size_t)i * DI * DS, Dpp + (size_t)i * DI, Qb, y);
        gemm_nt<<<dim3(DIM / BN, M_ROWS / BM), 256, 0, stream>>>(
            y, ow + (size_t)i * DIM * DI, nullptr, o, M_ROWS, DIM, DI);
        add_ln<<<M_ROWS, 256, 0, stream>>>(
            o, x, lng + (size_t)i * DIM, lnb + (size_t)i * DIM);
    }

    gemm_nt<<<dim3(VOCAB / BN, M_ROWS / BM), 256, 0, stream>>>(
        x, lm_w, lm_b, out, M_ROWS, VOCAB, DIM);
}

// Round 3
// 1361.983 us; speedup vs baseline: 5.1388x; 2.1618x over previous
//
#include <hip/hip_runtime.h>
#include <hip/hip_bf16.h>
#include <math.h>

#define BB 2
#define LL 1024
#define DIM 512
#define NL 6
#define DI 1024
#define DS 16
#define DC 4
#define DR 32
#define VOCAB 32000
#define M_ROWS (BB * LL)   // 2048
#define CCH 32             // scan chunks
#define CHLEN (LL / CCH)   // 32

typedef unsigned short u16;
typedef __attribute__((ext_vector_type(8))) short bf16x8;
typedef __attribute__((ext_vector_type(4))) float f32x4;

__device__ __forceinline__ u16 f2bf(float f) {
    unsigned u = __float_as_uint(f);
    u += 0x7FFF + ((u >> 16) & 1);       // round-to-nearest-even
    return (u16)(u >> 16);
}

// ---------------------------------------------------------------------------
// fp32 -> bf16 bulk cast (8 elems / thread)
// ---------------------------------------------------------------------------
__global__ __launch_bounds__(256) void cast_bf16(const float* __restrict__ in,
                                                 u16* __restrict__ out, int n8) {
    int idx = blockIdx.x * 256 + threadIdx.x;
    if (idx >= n8) return;
    float4 v0 = ((const float4*)in)[idx * 2];
    float4 v1 = ((const float4*)in)[idx * 2 + 1];
    union { u16 h[8]; int4 v; } r;
    r.h[0] = f2bf(v0.x); r.h[1] = f2bf(v0.y); r.h[2] = f2bf(v0.z); r.h[3] = f2bf(v0.w);
    r.h[4] = f2bf(v1.x); r.h[5] = f2bf(v1.y); r.h[6] = f2bf(v1.z); r.h[7] = f2bf(v1.w);
    ((int4*)out)[idx] = r.v;
}

// ---------------------------------------------------------------------------
// embed + pos  (writes f32 x and bf16 shadow xb)
// ---------------------------------------------------------------------------
__global__ __launch_bounds__(256) void embed_kernel(const int* __restrict__ tok,
                                                    const float* __restrict__ pos,
                                                    const float* __restrict__ emb,
                                                    float* __restrict__ x,
                                                    u16* __restrict__ xb) {
    int idx = blockIdx.x * 256 + threadIdx.x;           // B*L*DIM
    int d = idx & (DIM - 1);
    int l = (idx >> 9) & (LL - 1);
    int b = idx >> 19;
    int t = tok[b * LL + l];
    float v = emb[(size_t)t * DIM + d] + pos[l * DIM + d];
    x[idx] = v;
    xb[idx] = f2bf(v);
}

// ---------------------------------------------------------------------------
// bf16 MFMA GEMM:  C[M,N](f32) = A[M,K](bf16) * W[N,K](bf16)^T (+bias)
// 128x128 tile, BK=32, 4 waves (2x2), 16x16x32 MFMA, global_load_lds(16B)
// M,N,K all multiples of 128/128/32.
// ---------------------------------------------------------------------------
__global__ __launch_bounds__(256) void gemm_bf16(const u16* __restrict__ A,
                                                 const u16* __restrict__ W,
                                                 const float* __restrict__ bias,
                                                 float* __restrict__ C,
                                                 int M, int N, int K) {
    __shared__ __align__(16) u16 As[128 * 32];
    __shared__ __align__(16) u16 Ws[128 * 32];
    const int t = threadIdx.x;
    const int l = t & 63;
    const int w = t >> 6;                 // wave 0..3
    const int bm = blockIdx.y * 128;
    const int bn = blockIdx.x * 128;
    const int wm = (w >> 1) * 64;
    const int wn = (w & 1) * 64;

    f32x4 acc[4][4] = {};

    for (int k0 = 0; k0 < K; k0 += 32) {
#pragma unroll
        for (int p = 0; p < 2; ++p) {
            const int i = (p * 4 + w) * 64 + l;     // 0..511
            const int row = i >> 2;
            const int kq = i & 3;
            __builtin_amdgcn_global_load_lds(
                (const __attribute__((address_space(1))) unsigned int*)
                    (A + (size_t)(bm + row) * K + k0 + kq * 8),
                (__attribute__((address_space(3))) unsigned int*)
                    (As + (p * 4 + w) * 512),
                16, 0, 0);
            __builtin_amdgcn_global_load_lds(
                (const __attribute__((address_space(1))) unsigned int*)
                    (W + (size_t)(bn + row) * K + k0 + kq * 8),
                (__attribute__((address_space(3))) unsigned int*)
                    (Ws + (p * 4 + w) * 512),
                16, 0, 0);
        }
        asm volatile("s_waitcnt vmcnt(0)" ::: "memory");
        __syncthreads();
#pragma unroll
        for (int mi = 0; mi < 4; ++mi) {
            bf16x8 a = *(const bf16x8*)(As + (wm + mi * 16 + (l & 15)) * 32 + (l >> 4) * 8);
#pragma unroll
            for (int ni = 0; ni < 4; ++ni) {
                bf16x8 b = *(const bf16x8*)(Ws + (wn + ni * 16 + (l & 15)) * 32 + (l >> 4) * 8);
                acc[mi][ni] = __builtin_amdgcn_mfma_f32_16x16x32_bf16(a, b, acc[mi][ni], 0, 0, 0);
            }
        }
        __syncthreads();
    }

#pragma unroll
    for (int ni = 0; ni < 4; ++ni) {
        const int col = bn + wn + ni * 16 + (l & 15);
        const float bv = bias ? bias[col] : 0.f;
#pragma unroll
        for (int mi = 0; mi < 4; ++mi) {
            const int row = bm + wm + mi * 16 + ((l >> 4) << 2);
#pragma unroll
            for (int r = 0; r < 4; ++r)
                C[(size_t)(row + r) * N + col] = acc[mi][ni][r] + bv;
        }
    }
}

// ---------------------------------------------------------------------------
// Tiled fp32 GEMM (kept for x_proj, N=64):  C = A * W^T
// ---------------------------------------------------------------------------
#define BM 64
#define BN 64
#define BK 16
__global__ __launch_bounds__(256) void gemm_nt(const float* __restrict__ A,
                                               const float* __restrict__ W,
                                               const float* __restrict__ bias,
                                               float* __restrict__ C,
                                               int M, int N, int K) {
    __shared__ float As[BK][BM];
    __shared__ float Wsh[BK][BN];
    const int t = threadIdx.x;
    const int bm = blockIdx.y * BM;
    const int bn = blockIdx.x * BN;
    const int tx = t & 15;
    const int ty = t >> 4;
    const int row = t >> 2;
    const int quad = t & 3;

    float acc[4][4] = {};

    const float* Ap = A + (size_t)(bm + row) * K + quad * 4;
    const float* Wp = W + (size_t)(bn + row) * K + quad * 4;

    for (int k0 = 0; k0 < K; k0 += BK) {
        float4 av = *(const float4*)(Ap + k0);
        float4 wv = *(const float4*)(Wp + k0);
        __syncthreads();
        As[quad * 4 + 0][row] = av.x;
        As[quad * 4 + 1][row] = av.y;
        As[quad * 4 + 2][row] = av.z;
        As[quad * 4 + 3][row] = av.w;
        Wsh[quad * 4 + 0][row] = wv.x;
        Wsh[quad * 4 + 1][row] = wv.y;
        Wsh[quad * 4 + 2][row] = wv.z;
        Wsh[quad * 4 + 3][row] = wv.w;
        __syncthreads();
#pragma unroll
        for (int k = 0; k < BK; ++k) {
            float4 a = *(const float4*)&As[k][ty * 4];
            float4 wv2 = *(const float4*)&Wsh[k][tx * 4];
            acc[0][0] += a.x * wv2.x; acc[0][1] += a.x * wv2.y; acc[0][2] += a.x * wv2.z; acc[0][3] += a.x * wv2.w;
            acc[1][0] += a.y * wv2.x; acc[1][1] += a.y * wv2.y; acc[1][2] += a.y * wv2.z; acc[1][3] += a.y * wv2.w;
            acc[2][0] += a.z * wv2.x; acc[2][1] += a.z * wv2.y; acc[2][2] += a.z * wv2.z; acc[2][3] += a.z * wv2.w;
            acc[3][0] += a.w * wv2.x; acc[3][1] += a.w * wv2.y; acc[3][2] += a.w * wv2.z; acc[3][3] += a.w * wv2.w;
        }
    }
#pragma unroll
    for (int i = 0; i < 4; ++i) {
        float4 o;
        o.x = acc[i][0]; o.y = acc[i][1]; o.z = acc[i][2]; o.w = acc[i][3];
        *(float4*)(C + (size_t)(bm + ty * 4 + i) * N + bn + tx * 4) = o;
    }
}

// ---------------------------------------------------------------------------
// causal depthwise conv (DC=4) + SiLU
// ---------------------------------------------------------------------------
__global__ __launch_bounds__(256) void conv_silu(const float* __restrict__ xz,
                                                 const float* __restrict__ cw,
                                                 const float* __restrict__ cb,
                                                 float* __restrict__ xc) {
    int idx = blockIdx.x * 256 + threadIdx.x;   // B*L*DI
    int c = idx & (DI - 1);
    int l = (idx >> 10) & (LL - 1);
    int b = idx >> 20;
    float acc = cb[c];
#pragma unroll
    for (int k = 0; k < DC; ++k) {
        int ll = l + k - (DC - 1);
        if (ll >= 0)
            acc += cw[c * DC + k] * xz[((size_t)(b * LL + ll)) * (2 * DI) + c];
    }
    xc[idx] = acc / (1.f + __expf(-acc));
}

// ---------------------------------------------------------------------------
// dt = softplus(xdbl[:, :DR] @ dtw^T + dtb)
// ---------------------------------------------------------------------------
__global__ __launch_bounds__(256) void dtproj(const float* __restrict__ xdbl,
                                              const float* __restrict__ dtw,
                                              const float* __restrict__ dtb,
                                              float* __restrict__ dt) {
    __shared__ float xd[DR];
    int m = blockIdx.y;
    int t = threadIdx.x;
    if (t < DR) xd[t] = xdbl[(size_t)m * 64 + t];
    __syncthreads();
    int d = blockIdx.x * 256 + t;
    float acc = dtb[d];
    const float4* w4 = (const float4*)(dtw + (size_t)d * DR);
#pragma unroll
    for (int q = 0; q < DR / 4; ++q) {
        float4 w = w4[q];
        acc += w.x * xd[q * 4 + 0] + w.y * xd[q * 4 + 1] +
               w.z * xd[q * 4 + 2] + w.w * xd[q * 4 + 3];
    }
    float sp = (acc > 20.f) ? acc : log1pf(__expf(acc));
    dt[(size_t)m * DI + d] = sp;
}

// ---------------------------------------------------------------------------
// Chunked selective scan, pass 1
// ---------------------------------------------------------------------------
__global__ __launch_bounds__(256) void scan_pass1(const float* __restrict__ xc,
                                                  const float* __restrict__ dt,
                                                  const float* __restrict__ xdbl,
                                                  const float* __restrict__ A_log,
                                                  float* __restrict__ S,
                                                  float* __restrict__ Q) {
    const int d = blockIdx.x * 256 + threadIdx.x;
    const int b = blockIdx.y;
    const int c = blockIdx.z;
    float a[DS];
#pragma unroll
    for (int q = 0; q < 4; ++q) {
        float4 al = *(const float4*)(A_log + d * DS + q * 4);
        a[q * 4 + 0] = -__expf(al.x);
        a[q * 4 + 1] = -__expf(al.y);
        a[q * 4 + 2] = -__expf(al.z);
        a[q * 4 + 3] = -__expf(al.w);
    }
    float Qr[DS];
#pragma unroll
    for (int n = 0; n < DS; ++n) Qr[n] = 0.f;
    float Ssum = 0.f;

    const int l0 = c * CHLEN;
    const float* dtp = dt + ((size_t)b * LL + l0) * DI + d;
    const float* up  = xc + ((size_t)b * LL + l0) * DI + d;
    const float* xdp = xdbl + ((size_t)b * LL + l0) * 64 + DR;

    for (int l = 0; l < CHLEN; ++l) {
        float dtv = dtp[(size_t)l * DI];
        float uv  = up[(size_t)l * DI];
        float wv = dtv * uv;
        Ssum += dtv;
#pragma unroll
        for (int q = 0; q < 4; ++q) {
            float4 Bv = *(const float4*)(xdp + l * 64 + q * 4);
            float dA0 = __expf(dtv * a[q * 4 + 0]);
            float dA1 = __expf(dtv * a[q * 4 + 1]);
            float dA2 = __expf(dtv * a[q * 4 + 2]);
            float dA3 = __expf(dtv * a[q * 4 + 3]);
            Qr[q * 4 + 0] = dA0 * Qr[q * 4 + 0] + wv * Bv.x;
            Qr[q * 4 + 1] = dA1 * Qr[q * 4 + 1] + wv * Bv.y;
            Qr[q * 4 + 2] = dA2 * Qr[q * 4 + 2] + wv * Bv.z;
            Qr[q * 4 + 3] = dA3 * Qr[q * 4 + 3] + wv * Bv.w;
        }
    }
    S[((size_t)b * CCH + c) * DI + d] = Ssum;
    float* Qp = Q + (((size_t)b * CCH + c) * DI + d) * DS;
#pragma unroll
    for (int q = 0; q < 4; ++q) {
        float4 o;
        o.x = Qr[q * 4 + 0]; o.y = Qr[q * 4 + 1];
        o.z = Qr[q * 4 + 2]; o.w = Qr[q * 4 + 3];
        *(float4*)(Qp + q * 4) = o;
    }
}

// ---------------------------------------------------------------------------
// Pass 2: sequential combine over chunks
// ---------------------------------------------------------------------------
__global__ __launch_bounds__(256) void scan_pass2(const float* __restrict__ A_log,
                                                  const float* __restrict__ S,
                                                  float* __restrict__ Q) {
    const int idx = blockIdx.x * 256 + threadIdx.x;
    const int b = idx >> 14;
    const int dn = idx & 16383;
    const int d = dn >> 4;
    const float a = -__expf(A_log[dn]);
    float h = 0.f;
    for (int c = 0; c < CCH; ++c) {
        const size_t soff = ((size_t)b * CCH + c) * DI + d;
        const size_t qoff = ((size_t)b * CCH + c) * (size_t)(DI * DS) + dn;
        float P = __expf(a * S[soff]);
        float q = Q[qoff];
        Q[qoff] = h;
        h = P * h + q;
    }
}

// ---------------------------------------------------------------------------
// Pass 3: per-chunk recurrence from start state; gated output as bf16
// ---------------------------------------------------------------------------
__global__ __launch_bounds__(256) void scan_pass3(const float* __restrict__ xc,
                                                  const float* __restrict__ dt,
                                                  const float* __restrict__ xdbl,
                                                  const float* __restrict__ xz,
                                                  const float* __restrict__ A_log,
                                                  const float* __restrict__ Dpp,
                                                  const float* __restrict__ Q,
                                                  u16* __restrict__ y) {
    const int d = blockIdx.x * 256 + threadIdx.x;
    const int b = blockIdx.y;
    const int c = blockIdx.z;
    float a[DS];
#pragma unroll
    for (int q = 0; q < 4; ++q) {
        float4 al = *(const float4*)(A_log + d * DS + q * 4);
        a[q * 4 + 0] = -__expf(al.x);
        a[q * 4 + 1] = -__expf(al.y);
        a[q * 4 + 2] = -__expf(al.z);
        a[q * 4 + 3] = -__expf(al.w);
    }
    float h[DS];
    const float* Qp = Q + (((size_t)b * CCH + c) * DI + d) * DS;
#pragma unroll
    for (int q = 0; q < 4; ++q) {
        float4 hv = *(const float4*)(Qp + q * 4);
        h[q * 4 + 0] = hv.x; h[q * 4 + 1] = hv.y;
        h[q * 4 + 2] = hv.z; h[q * 4 + 3] = hv.w;
    }
    const float dp = Dpp[d];

    const int l0 = c * CHLEN;
    const float* dtp = dt + ((size_t)b * LL + l0) * DI + d;
    const float* up  = xc + ((size_t)b * LL + l0) * DI + d;
    const float* xdp = xdbl + ((size_t)b * LL + l0) * 64 + DR;
    const float* zp  = xz + ((size_t)b * LL + l0) * (2 * DI) + DI + d;
    u16* yp = y + ((size_t)b * LL + l0) * DI + d;

    for (int l = 0; l < CHLEN; ++l) {
        float dtv = dtp[(size_t)l * DI];
        float uv  = up[(size_t)l * DI];
        float wv = dtv * uv;
        float p = 0.f;
#pragma unroll
        for (int q = 0; q < 4; ++q) {
            float4 Bv = *(const float4*)(xdp + l * 64 + q * 4);
            float4 Cv = *(const float4*)(xdp + l * 64 + 16 + q * 4);
            float dA0 = __expf(dtv * a[q * 4 + 0]);
            float dA1 = __expf(dtv * a[q * 4 + 1]);
            float dA2 = __expf(dtv * a[q * 4 + 2]);
            float dA3 = __expf(dtv * a[q * 4 + 3]);
            h[q * 4 + 0] = dA0 * h[q * 4 + 0] + wv * Bv.x;
            h[q * 4 + 1] = dA1 * h[q * 4 + 1] + wv * Bv.y;
            h[q * 4 + 2] = dA2 * h[q * 4 + 2] + wv * Bv.z;
            h[q * 4 + 3] = dA3 * h[q * 4 + 3] + wv * Bv.w;
            p += h[q * 4 + 0] * Cv.x + h[q * 4 + 1] * Cv.y +
                 h[q * 4 + 2] * Cv.z + h[q * 4 + 3] * Cv.w;
        }
        float zv = zp[(size_t)l * (2 * DI)];
        float g = zv / (1.f + __expf(-zv));
        yp[(size_t)l * DI] = f2bf((p + uv * dp) * g);
    }
}

// ---------------------------------------------------------------------------
// x = LayerNorm(x + o) * g + b   (also writes bf16 shadow xb)
// ---------------------------------------------------------------------------
__global__ __launch_bounds__(256) void add_ln(const float* __restrict__ o,
                                              float* __restrict__ x,
                                              const float* __restrict__ g,
                                              const float* __restrict__ b,
                                              u16* __restrict__ xb) {
    int m = blockIdx.x;
    int t = threadIdx.x;
    const float* xr = x + (size_t)m * DIM;
    const float* orr = o + (size_t)m * DIM;
    float v0 = xr[t] + orr[t];
    float v1 = xr[t + 256] + orr[t + 256];
    float s = v0 + v1;
    float ss = v0 * v0 + v1 * v1;
#pragma unroll
    for (int off = 32; off > 0; off >>= 1) {
        s += __shfl_down(s, off, 64);
        ss += __shfl_down(ss, off, 64);
    }
    __shared__ float sb[4], ssb[4];
    int w = t >> 6;
    if ((t & 63) == 0) { sb[w] = s; ssb[w] = ss; }
    __syncthreads();
    float stot = sb[0] + sb[1] + sb[2] + sb[3];
    float sstot = ssb[0] + ssb[1] + ssb[2] + ssb[3];
    float mean = stot * (1.f / DIM);
    float var = sstot * (1.f / DIM) - mean * mean;
    float rs = rsqrtf(var + 1e-5f);
    float* xw = x + (size_t)m * DIM;
    float o0 = (v0 - mean) * rs * g[t] + b[t];
    float o1 = (v1 - mean) * rs * g[t + 256] + b[t + 256];
    xw[t] = o0;
    xw[t + 256] = o1;
    xb[(size_t)m * DIM + t] = f2bf(o0);
    xb[(size_t)m * DIM + t + 256] = f2bf(o1);
}

// ---------------------------------------------------------------------------
extern "C" void kernel_launch(void* const* d_in, const int* in_sizes, int n_in,
                              void* d_out, int out_size, void* d_ws, size_t ws_size,
                              hipStream_t stream) {
    const int*   tokens = (const int*)d_in[0];
    const float* pos    = (const float*)d_in[1];
    const float* emb    = (const float*)d_in[2];
    const float* lm_w   = (const float*)d_in[3];
    const float* lm_b   = (const float*)d_in[4];
    const float* in_w   = (const float*)d_in[5];
    const float* cw     = (const float*)d_in[6];
    const float* cb     = (const float*)d_in[7];
    const float* xpw    = (const float*)d_in[8];
    const float* dtw    = (const float*)d_in[9];
    const float* dtb    = (const float*)d_in[10];
    const float* A_log  = (const float*)d_in[11];
    const float* Dpp    = (const float*)d_in[12];
    const float* ow     = (const float*)d_in[13];
    const float* lng    = (const float*)d_in[14];
    const float* lnb    = (const float*)d_in[15];
    float* out = (float*)d_out;

    float* ws = (float*)d_ws;
    float* x    = ws;                   // 1048576 f32
    float* xz   = x + 1048576;          // 4194304
    float* xc   = xz + 4194304;         // 2097152
    float* xd   = xc + 2097152;         // 131072
    float* dt   = xd + 131072;          // 2097152
    float* o    = dt + 2097152;         // 1048576
    float* S    = o + 1048576;          // 65536
    float* Qb   = S + 65536;            // 1048576
    u16* xb     = (u16*)(Qb + 1048576); // 1048576 u16
    u16* yb     = xb + 1048576;         // 2097152
    u16* lm_wb  = yb + 2097152;         // 16384000
    u16* in_wb  = lm_wb + 16384000;     // 6291456
    u16* owb    = in_wb + 6291456;      // 3145728

    // one-time (per launch) weight casts
    cast_bf16<<<16384000 / 8 / 256, 256, 0, stream>>>(lm_w, lm_wb, 16384000 / 8);
    cast_bf16<<<6291456 / 8 / 256, 256, 0, stream>>>(in_w, in_wb, 6291456 / 8);
    cast_bf16<<<3145728 / 8 / 256, 256, 0, stream>>>(ow, owb, 3145728 / 8);

    embed_kernel<<<M_ROWS * DIM / 256, 256, 0, stream>>>(tokens, pos, emb, x, xb);

    for (int i = 0; i < NL; ++i) {
        gemm_bf16<<<dim3((2 * DI) / 128, M_ROWS / 128), 256, 0, stream>>>(
            xb, in_wb + (size_t)i * (2 * DI) * DIM, nullptr, xz, M_ROWS, 2 * DI, DIM);
        conv_silu<<<M_ROWS * DI / 256, 256, 0, stream>>>(
            xz, cw + (size_t)i * DI * DC, cb + (size_t)i * DI, xc);
        gemm_nt<<<dim3(64 / BN, M_ROWS / BM), 256, 0, stream>>>(
            xc, xpw + (size_t)i * 64 * DI, nullptr, xd, M_ROWS, 64, DI);
        dtproj<<<dim3(DI / 256, M_ROWS), 256, 0, stream>>>(
            xd, dtw + (size_t)i * DI * DR, dtb + (size_t)i * DI, dt);
        scan_pass1<<<dim3(DI / 256, BB, CCH), 256, 0, stream>>>(
            xc, dt, xd, A_log + (size_t)i * DI * DS, S, Qb);
        scan_pass2<<<(BB * DI * DS) / 256, 256, 0, stream>>>(
            A_log + (size_t)i * DI * DS, S, Qb);
        scan_pass3<<<dim3(DI / 256, BB, CCH), 256, 0, stream>>>(
            xc, dt, xd, xz, A_log + (size_t)i * DI * DS, Dpp + (size_t)i * DI, Qb, yb);
        gemm_bf16<<<dim3(DIM / 128, M_ROWS / 128), 256, 0, stream>>>(
            yb, owb + (size_t)i * DIM * DI, nullptr, o, M_ROWS, DIM, DI);
        add_ln<<<M_ROWS, 256, 0, stream>>>(
            o, x, lng + (size_t)i * DIM, lnb + (size_t)i * DIM, xb);
    }

    gemm_bf16<<<dim3(VOCAB / 128, M_ROWS / 128), 256, 0, stream>>>(
        xb, lm_wb, lm_b, out, M_ROWS, VOCAB, DIM);
}

// Round 4
// 955.376 us; speedup vs baseline: 7.3259x; 1.4256x over previous
//
#include <hip/hip_runtime.h>
#include <hip/hip_bf16.h>
#include <math.h>

#define BB 2
#define LL 1024
#define DIM 512
#define NL 6
#define DI 1024
#define DS 16
#define DC 4
#define DR 32
#define VOCAB 32000
#define M_ROWS (BB * LL)   // 2048
#define CCH 32             // scan chunks
#define CHLEN (LL / CCH)   // 32
#define KSPLIT 8           // x_proj K-split

typedef unsigned short u16;
typedef __attribute__((ext_vector_type(8))) short bf16x8;
typedef __attribute__((ext_vector_type(4))) float f32x4;

__device__ __forceinline__ u16 f2bf(float f) {
    unsigned u = __float_as_uint(f);
    u += 0x7FFF + ((u >> 16) & 1);       // round-to-nearest-even
    return (u16)(u >> 16);
}
// LDS chunk swizzle: row r, 16B-chunk c -> c ^ ((r>>1)&3)  (involution)
#define SWZ(r, c) ((c) ^ (((r) >> 1) & 3))

// ---------------------------------------------------------------------------
// fp32 -> bf16 bulk cast
// ---------------------------------------------------------------------------
__global__ __launch_bounds__(256) void cast_bf16(const float* __restrict__ in,
                                                 u16* __restrict__ out, int n8) {
    int idx = blockIdx.x * 256 + threadIdx.x;
    if (idx >= n8) return;
    float4 v0 = ((const float4*)in)[idx * 2];
    float4 v1 = ((const float4*)in)[idx * 2 + 1];
    union { u16 h[8]; int4 v; } r;
    r.h[0] = f2bf(v0.x); r.h[1] = f2bf(v0.y); r.h[2] = f2bf(v0.z); r.h[3] = f2bf(v0.w);
    r.h[4] = f2bf(v1.x); r.h[5] = f2bf(v1.y); r.h[6] = f2bf(v1.z); r.h[7] = f2bf(v1.w);
    ((int4*)out)[idx] = r.v;
}

// ---------------------------------------------------------------------------
// embed + pos  (f32 x + bf16 shadow xb)
// ---------------------------------------------------------------------------
__global__ __launch_bounds__(256) void embed_kernel(const int* __restrict__ tok,
                                                    const float* __restrict__ pos,
                                                    const float* __restrict__ emb,
                                                    float* __restrict__ x,
                                                    u16* __restrict__ xb) {
    int idx = blockIdx.x * 256 + threadIdx.x;
    int d = idx & (DIM - 1);
    int l = (idx >> 9) & (LL - 1);
    int b = idx >> 19;
    int t = tok[b * LL + l];
    float v = emb[(size_t)t * DIM + d] + pos[l * DIM + d];
    x[idx] = v;
    xb[idx] = f2bf(v);
}

// ---------------------------------------------------------------------------
// bf16 MFMA GEMM, 128x128 tile, BK=32.  C[M,N](f32) = A * W^T.
// Swapped-operand epilogue (float4 col-contiguous stores), XCD-chunked
// swizzle (N-major logical), LDS chunk XOR-swizzle.
// mode 0: C = acc (+bias);  mode 1: C = softplus(acc + bias)
// ---------------------------------------------------------------------------
__global__ __launch_bounds__(256) void gemm_bf16(const u16* __restrict__ A,
                                                 const u16* __restrict__ W,
                                                 const float* __restrict__ bias,
                                                 float* __restrict__ C,
                                                 int M, int N, int K,
                                                 int lda, int ldw, int mode) {
    __shared__ __align__(16) u16 As[128 * 32];
    __shared__ __align__(16) u16 Ws[128 * 32];
    const int t = threadIdx.x;
    const int l = t & 63;
    const int w = t >> 6;
    // bijective XCD swizzle (m204), logical order: bn-major, bm fastest
    const int nwg = gridDim.x;
    const int q = nwg >> 3, r8 = nwg & 7;
    const int xcd = blockIdx.x & 7, rank = blockIdx.x >> 3;
    const int wgid = (xcd < r8 ? xcd * (q + 1) : r8 * (q + 1) + (xcd - r8) * q) + rank;
    const int Mb = M >> 7;
    const int bm = (wgid % Mb) * 128;
    const int bn = (wgid / Mb) * 128;
    const int wm = (w >> 1) * 64;
    const int wn = (w & 1) * 64;

    f32x4 acc[4][4] = {};

    for (int k0 = 0; k0 < K; k0 += 32) {
#pragma unroll
        for (int p = 0; p < 2; ++p) {
            const int i = (p * 4 + w) * 64 + l;     // 0..511
            const int row = i >> 2;
            const int kq = SWZ(row, i & 3);
            __builtin_amdgcn_global_load_lds(
                (const __attribute__((address_space(1))) unsigned int*)
                    (A + (size_t)(bm + row) * lda + k0 + kq * 8),
                (__attribute__((address_space(3))) unsigned int*)
                    (As + (p * 4 + w) * 512),
                16, 0, 0);
            __builtin_amdgcn_global_load_lds(
                (const __attribute__((address_space(1))) unsigned int*)
                    (W + (size_t)(bn + row) * ldw + k0 + kq * 8),
                (__attribute__((address_space(3))) unsigned int*)
                    (Ws + (p * 4 + w) * 512),
                16, 0, 0);
        }
        asm volatile("s_waitcnt vmcnt(0)" ::: "memory");
        __syncthreads();
#pragma unroll
        for (int mi = 0; mi < 4; ++mi) {
            const int ar = wm + mi * 16 + (l & 15);
            bf16x8 a = *(const bf16x8*)(As + ar * 32 + SWZ(ar, l >> 4) * 8);
#pragma unroll
            for (int ni = 0; ni < 4; ++ni) {
                const int wr = wn + ni * 16 + (l & 15);
                bf16x8 b = *(const bf16x8*)(Ws + wr * 32 + SWZ(wr, l >> 4) * 8);
                // swapped: D[row = a-idx = l&15.., col = (l>>4)*4+r over W-idx]
                acc[mi][ni] = __builtin_amdgcn_mfma_f32_16x16x32_bf16(b, a, acc[mi][ni], 0, 0, 0);
            }
        }
        __syncthreads();
    }

#pragma unroll
    for (int mi = 0; mi < 4; ++mi) {
        const int row = bm + wm + mi * 16 + (l & 15);
#pragma unroll
        for (int ni = 0; ni < 4; ++ni) {
            const int col = bn + wn + ni * 16 + ((l >> 4) << 2);
            float4 v;
            v.x = acc[mi][ni][0]; v.y = acc[mi][ni][1];
            v.z = acc[mi][ni][2]; v.w = acc[mi][ni][3];
            if (bias != nullptr) {
                float4 b4 = *(const float4*)(bias + col);
                v.x += b4.x; v.y += b4.y; v.z += b4.z; v.w += b4.w;
            }
            if (mode == 1) {
                v.x = (v.x > 20.f) ? v.x : log1pf(__expf(v.x));
                v.y = (v.y > 20.f) ? v.y : log1pf(__expf(v.y));
                v.z = (v.z > 20.f) ? v.z : log1pf(__expf(v.z));
                v.w = (v.w > 20.f) ? v.w : log1pf(__expf(v.w));
            }
            *(float4*)(C + (size_t)row * N + col) = v;
        }
    }
}

// ---------------------------------------------------------------------------
// bf16 MFMA GEMM, 128M x 64N tile, BK=32, optional K-split.
// grid = (ksplit, M/128, N/64).  out += kz * pstride (caller bakes layout).
// ---------------------------------------------------------------------------
__global__ __launch_bounds__(256) void gemm_n64(const u16* __restrict__ A,
                                                const u16* __restrict__ W,
                                                float* __restrict__ out,
                                                int lda, int ldw, int ldc,
                                                int KS, int pstride) {
    __shared__ __align__(16) u16 As[128 * 32];
    __shared__ __align__(16) u16 Ws[64 * 32];
    const int t = threadIdx.x;
    const int l = t & 63;
    const int w = t >> 6;
    const int kz = blockIdx.x;
    const int bm = blockIdx.y * 128;
    const int bnn = blockIdx.z * 64;
    const int wm = w * 32;

    f32x4 acc[2][4] = {};

    const int kbeg = kz * KS;
    for (int k0 = kbeg; k0 < kbeg + KS; k0 += 32) {
#pragma unroll
        for (int p = 0; p < 2; ++p) {
            const int i = p * 256 + w * 64 + l;     // 0..511
            const int row = i >> 2;
            const int kq = SWZ(row, i & 3);
            __builtin_amdgcn_global_load_lds(
                (const __attribute__((address_space(1))) unsigned int*)
                    (A + (size_t)(bm + row) * lda + k0 + kq * 8),
                (__attribute__((address_space(3))) unsigned int*)
                    (As + (p * 256 + w * 64) * 8),
                16, 0, 0);
        }
        {
            const int i = w * 64 + l;               // 0..255
            const int row = i >> 2;
            const int kq = SWZ(row, i & 3);
            __builtin_amdgcn_global_load_lds(
                (const __attribute__((address_space(1))) unsigned int*)
                    (W + (size_t)(bnn + row) * ldw + k0 + kq * 8),
                (__attribute__((address_space(3))) unsigned int*)
                    (Ws + (w * 64) * 8),
                16, 0, 0);
        }
        asm volatile("s_waitcnt vmcnt(0)" ::: "memory");
        __syncthreads();
#pragma unroll
        for (int mi = 0; mi < 2; ++mi) {
            const int ar = wm + mi * 16 + (l & 15);
            bf16x8 a = *(const bf16x8*)(As + ar * 32 + SWZ(ar, l >> 4) * 8);
#pragma unroll
            for (int ni = 0; ni < 4; ++ni) {
                const int wr = ni * 16 + (l & 15);
                bf16x8 b = *(const bf16x8*)(Ws + wr * 32 + SWZ(wr, l >> 4) * 8);
                acc[mi][ni] = __builtin_amdgcn_mfma_f32_16x16x32_bf16(b, a, acc[mi][ni], 0, 0, 0);
            }
        }
        __syncthreads();
    }

    float* op = out + (size_t)kz * pstride;
#pragma unroll
    for (int mi = 0; mi < 2; ++mi) {
        const int row = bm + wm + mi * 16 + (l & 15);
#pragma unroll
        for (int ni = 0; ni < 4; ++ni) {
            const int col = bnn + ni * 16 + ((l >> 4) << 2);
            float4 v;
            v.x = acc[mi][ni][0]; v.y = acc[mi][ni][1];
            v.z = acc[mi][ni][2]; v.w = acc[mi][ni][3];
            *(float4*)(op + (size_t)row * ldc + col) = v;
        }
    }
}

// ---------------------------------------------------------------------------
// x_proj K-split reduce -> xd (f32) + xdb (bf16)
// ---------------------------------------------------------------------------
__global__ __launch_bounds__(256) void xdreduce(const float* __restrict__ Pf,
                                                float* __restrict__ xd,
                                                u16* __restrict__ xdb) {
    int idx = blockIdx.x * 256 + threadIdx.x;   // 2048*64
    float s = 0.f;
#pragma unroll
    for (int kz = 0; kz < KSPLIT; ++kz)
        s += Pf[(size_t)kz * (M_ROWS * 64) + idx];
    xd[idx] = s;
    xdb[idx] = f2bf(s);
}

// ---------------------------------------------------------------------------
// causal depthwise conv (DC=4) + SiLU  -> xc f32 + xcb bf16
// ---------------------------------------------------------------------------
__global__ __launch_bounds__(256) void conv_silu(const float* __restrict__ xz,
                                                 const float* __restrict__ cw,
                                                 const float* __restrict__ cb,
                                                 float* __restrict__ xc,
                                                 u16* __restrict__ xcb) {
    int idx = blockIdx.x * 256 + threadIdx.x;   // B*L*DI
    int c = idx & (DI - 1);
    int l = (idx >> 10) & (LL - 1);
    int b = idx >> 20;
    float acc = cb[c];
#pragma unroll
    for (int k = 0; k < DC; ++k) {
        int ll = l + k - (DC - 1);
        if (ll >= 0)
            acc += cw[c * DC + k] * xz[((size_t)(b * LL + ll)) * (2 * DI) + c];
    }
    float v = acc / (1.f + __expf(-acc));
    xc[idx] = v;
    xcb[idx] = f2bf(v);
}

// ---------------------------------------------------------------------------
// Chunked selective scan, pass 1
// ---------------------------------------------------------------------------
__global__ __launch_bounds__(256) void scan_pass1(const float* __restrict__ xc,
                                                  const float* __restrict__ dt,
                                                  const float* __restrict__ xdbl,
                                                  const float* __restrict__ A_log,
                                                  float* __restrict__ S,
                                                  float* __restrict__ Q) {
    const int d = blockIdx.x * 256 + threadIdx.x;
    const int b = blockIdx.y;
    const int c = blockIdx.z;
    float a[DS];
#pragma unroll
    for (int q = 0; q < 4; ++q) {
        float4 al = *(const float4*)(A_log + d * DS + q * 4);
        a[q * 4 + 0] = -__expf(al.x);
        a[q * 4 + 1] = -__expf(al.y);
        a[q * 4 + 2] = -__expf(al.z);
        a[q * 4 + 3] = -__expf(al.w);
    }
    float Qr[DS];
#pragma unroll
    for (int n = 0; n < DS; ++n) Qr[n] = 0.f;
    float Ssum = 0.f;

    const int l0 = c * CHLEN;
    const float* dtp = dt + ((size_t)b * LL + l0) * DI + d;
    const float* up  = xc + ((size_t)b * LL + l0) * DI + d;
    const float* xdp = xdbl + ((size_t)b * LL + l0) * 64 + DR;

    for (int l = 0; l < CHLEN; ++l) {
        float dtv = dtp[(size_t)l * DI];
        float uv  = up[(size_t)l * DI];
        float wv = dtv * uv;
        Ssum += dtv;
#pragma unroll
        for (int q = 0; q < 4; ++q) {
            float4 Bv = *(const float4*)(xdp + l * 64 + q * 4);
            float dA0 = __expf(dtv * a[q * 4 + 0]);
            float dA1 = __expf(dtv * a[q * 4 + 1]);
            float dA2 = __expf(dtv * a[q * 4 + 2]);
            float dA3 = __expf(dtv * a[q * 4 + 3]);
            Qr[q * 4 + 0] = dA0 * Qr[q * 4 + 0] + wv * Bv.x;
            Qr[q * 4 + 1] = dA1 * Qr[q * 4 + 1] + wv * Bv.y;
            Qr[q * 4 + 2] = dA2 * Qr[q * 4 + 2] + wv * Bv.z;
            Qr[q * 4 + 3] = dA3 * Qr[q * 4 + 3] + wv * Bv.w;
        }
    }
    S[((size_t)b * CCH + c) * DI + d] = Ssum;
    float* Qp = Q + (((size_t)b * CCH + c) * DI + d) * DS;
#pragma unroll
    for (int q = 0; q < 4; ++q) {
        float4 o;
        o.x = Qr[q * 4 + 0]; o.y = Qr[q * 4 + 1];
        o.z = Qr[q * 4 + 2]; o.w = Qr[q * 4 + 3];
        *(float4*)(Qp + q * 4) = o;
    }
}

// ---------------------------------------------------------------------------
// Pass 2: sequential combine over chunks
// ---------------------------------------------------------------------------
__global__ __launch_bounds__(256) void scan_pass2(const float* __restrict__ A_log,
                                                  const float* __restrict__ S,
                                                  float* __restrict__ Q) {
    const int idx = blockIdx.x * 256 + threadIdx.x;
    const int b = idx >> 14;
    const int dn = idx & 16383;
    const int d = dn >> 4;
    const float a = -__expf(A_log[dn]);
    float h = 0.f;
    for (int c = 0; c < CCH; ++c) {
        const size_t soff = ((size_t)b * CCH + c) * DI + d;
        const size_t qoff = ((size_t)b * CCH + c) * (size_t)(DI * DS) + dn;
        float P = __expf(a * S[soff]);
        float qv = Q[qoff];
        Q[qoff] = h;
        h = P * h + qv;
    }
}

// ---------------------------------------------------------------------------
// Pass 3: per-chunk recurrence; gated bf16 output
// ---------------------------------------------------------------------------
__global__ __launch_bounds__(256) void scan_pass3(const float* __restrict__ xc,
                                                  const float* __restrict__ dt,
                                                  const float* __restrict__ xdbl,
                                                  const float* __restrict__ xz,
                                                  const float* __restrict__ A_log,
                                                  const float* __restrict__ Dpp,
                                                  const float* __restrict__ Q,
                                                  u16* __restrict__ y) {
    const int d = blockIdx.x * 256 + threadIdx.x;
    const int b = blockIdx.y;
    const int c = blockIdx.z;
    float a[DS];
#pragma unroll
    for (int q = 0; q < 4; ++q) {
        float4 al = *(const float4*)(A_log + d * DS + q * 4);
        a[q * 4 + 0] = -__expf(al.x);
        a[q * 4 + 1] = -__expf(al.y);
        a[q * 4 + 2] = -__expf(al.z);
        a[q * 4 + 3] = -__expf(al.w);
    }
    float h[DS];
    const float* Qp = Q + (((size_t)b * CCH + c) * DI + d) * DS;
#pragma unroll
    for (int q = 0; q < 4; ++q) {
        float4 hv = *(const float4*)(Qp + q * 4);
        h[q * 4 + 0] = hv.x; h[q * 4 + 1] = hv.y;
        h[q * 4 + 2] = hv.z; h[q * 4 + 3] = hv.w;
    }
    const float dp = Dpp[d];

    const int l0 = c * CHLEN;
    const float* dtp = dt + ((size_t)b * LL + l0) * DI + d;
    const float* up  = xc + ((size_t)b * LL + l0) * DI + d;
    const float* xdp = xdbl + ((size_t)b * LL + l0) * 64 + DR;
    const float* zp  = xz + ((size_t)b * LL + l0) * (2 * DI) + DI + d;
    u16* yp = y + ((size_t)b * LL + l0) * DI + d;

    for (int l = 0; l < CHLEN; ++l) {
        float dtv = dtp[(size_t)l * DI];
        float uv  = up[(size_t)l * DI];
        float wv = dtv * uv;
        float p = 0.f;
#pragma unroll
        for (int q = 0; q < 4; ++q) {
            float4 Bv = *(const float4*)(xdp + l * 64 + q * 4);
            float4 Cv = *(const float4*)(xdp + l * 64 + 16 + q * 4);
            float dA0 = __expf(dtv * a[q * 4 + 0]);
            float dA1 = __expf(dtv * a[q * 4 + 1]);
            float dA2 = __expf(dtv * a[q * 4 + 2]);
            float dA3 = __expf(dtv * a[q * 4 + 3]);
            h[q * 4 + 0] = dA0 * h[q * 4 + 0] + wv * Bv.x;
            h[q * 4 + 1] = dA1 * h[q * 4 + 1] + wv * Bv.y;
            h[q * 4 + 2] = dA2 * h[q * 4 + 2] + wv * Bv.z;
            h[q * 4 + 3] = dA3 * h[q * 4 + 3] + wv * Bv.w;
            p += h[q * 4 + 0] * Cv.x + h[q * 4 + 1] * Cv.y +
                 h[q * 4 + 2] * Cv.z + h[q * 4 + 3] * Cv.w;
        }
        float zv = zp[(size_t)l * (2 * DI)];
        float g = zv / (1.f + __expf(-zv));
        yp[(size_t)l * DI] = f2bf((p + uv * dp) * g);
    }
}

// ---------------------------------------------------------------------------
// x = LayerNorm(x + o) * g + b   (+ bf16 shadow)
// ---------------------------------------------------------------------------
__global__ __launch_bounds__(256) void add_ln(const float* __restrict__ o,
                                              float* __restrict__ x,
                                              const float* __restrict__ g,
                                              const float* __restrict__ b,
                                              u16* __restrict__ xb) {
    int m = blockIdx.x;
    int t = threadIdx.x;
    const float* xr = x + (size_t)m * DIM;
    const float* orr = o + (size_t)m * DIM;
    float v0 = xr[t] + orr[t];
    float v1 = xr[t + 256] + orr[t + 256];
    float s = v0 + v1;
    float ss = v0 * v0 + v1 * v1;
#pragma unroll
    for (int off = 32; off > 0; off >>= 1) {
        s += __shfl_down(s, off, 64);
        ss += __shfl_down(ss, off, 64);
    }
    __shared__ float sb[4], ssb[4];
    int w = t >> 6;
    if ((t & 63) == 0) { sb[w] = s; ssb[w] = ss; }
    __syncthreads();
    float stot = sb[0] + sb[1] + sb[2] + sb[3];
    float sstot = ssb[0] + ssb[1] + ssb[2] + ssb[3];
    float mean = stot * (1.f / DIM);
    float var = sstot * (1.f / DIM) - mean * mean;
    float rs = rsqrtf(var + 1e-5f);
    float* xw = x + (size_t)m * DIM;
    float o0 = (v0 - mean) * rs * g[t] + b[t];
    float o1 = (v1 - mean) * rs * g[t + 256] + b[t + 256];
    xw[t] = o0;
    xw[t + 256] = o1;
    xb[(size_t)m * DIM + t] = f2bf(o0);
    xb[(size_t)m * DIM + t + 256] = f2bf(o1);
}

// ---------------------------------------------------------------------------
extern "C" void kernel_launch(void* const* d_in, const int* in_sizes, int n_in,
                              void* d_out, int out_size, void* d_ws, size_t ws_size,
                              hipStream_t stream) {
    const int*   tokens = (const int*)d_in[0];
    const float* pos    = (const float*)d_in[1];
    const float* emb    = (const float*)d_in[2];
    const float* lm_w   = (const float*)d_in[3];
    const float* lm_b   = (const float*)d_in[4];
    const float* in_w   = (const float*)d_in[5];
    const float* cw     = (const float*)d_in[6];
    const float* cb     = (const float*)d_in[7];
    const float* xpw    = (const float*)d_in[8];
    const float* dtw    = (const float*)d_in[9];
    const float* dtb    = (const float*)d_in[10];
    const float* A_log  = (const float*)d_in[11];
    const float* Dpp    = (const float*)d_in[12];
    const float* ow     = (const float*)d_in[13];
    const float* lng    = (const float*)d_in[14];
    const float* lnb    = (const float*)d_in[15];
    float* out = (float*)d_out;

    float* ws = (float*)d_ws;
    float* x    = ws;                   // 1048576
    float* xz   = x + 1048576;          // 4194304
    float* xc   = xz + 4194304;         // 2097152
    float* xd   = xc + 2097152;         // 131072
    float* dt   = xd + 131072;          // 2097152
    float* o    = dt + 2097152;         // 1048576
    float* S    = o + 1048576;          // 65536
    float* Qb   = S + 65536;            // 1048576
    float* Pf   = Qb + 1048576;         // KSPLIT*2048*64 = 1048576
    u16* xb     = (u16*)(Pf + 1048576); // 1048576
    u16* yb     = xb + 1048576;         // 2097152
    u16* xcb    = yb + 2097152;         // 2097152
    u16* xdb    = xcb + 2097152;        // 131072
    u16* lm_wb  = xdb + 131072;         // 16384000
    u16* in_wb  = lm_wb + 16384000;     // 6291456
    u16* owb    = in_wb + 6291456;      // 3145728
    u16* xpwb   = owb + 3145728;        // 393216
    u16* dtwb   = xpwb + 393216;        // 196608

    cast_bf16<<<16384000 / 8 / 256, 256, 0, stream>>>(lm_w, lm_wb, 16384000 / 8);
    cast_bf16<<<6291456 / 8 / 256, 256, 0, stream>>>(in_w, in_wb, 6291456 / 8);
    cast_bf16<<<3145728 / 8 / 256, 256, 0, stream>>>(ow, owb, 3145728 / 8);
    cast_bf16<<<393216 / 8 / 256, 256, 0, stream>>>(xpw, xpwb, 393216 / 8);
    cast_bf16<<<196608 / 8 / 256, 256, 0, stream>>>(dtw, dtwb, 196608 / 8);

    embed_kernel<<<M_ROWS * DIM / 256, 256, 0, stream>>>(tokens, pos, emb, x, xb);

    for (int i = 0; i < NL; ++i) {
        // in_proj: (2048x2048x512)
        gemm_bf16<<<(2048 / 128) * (M_ROWS / 128), 256, 0, stream>>>(
            xb, in_wb + (size_t)i * 2048 * 512, nullptr, xz,
            M_ROWS, 2048, 512, 512, 512, 0);
        conv_silu<<<M_ROWS * DI / 256, 256, 0, stream>>>(
            xz, cw + (size_t)i * DI * DC, cb + (size_t)i * DI, xc, xcb);
        // x_proj: (2048x64x1024), K-split 8 -> Pf
        gemm_n64<<<dim3(KSPLIT, M_ROWS / 128, 1), 256, 0, stream>>>(
            xcb, xpwb + (size_t)i * 64 * 1024, Pf,
            1024, 1024, 64, 1024 / KSPLIT, M_ROWS * 64);
        xdreduce<<<M_ROWS * 64 / 256, 256, 0, stream>>>(Pf, xd, xdb);
        // dt: softplus(xd[:, :32] @ dtw^T + dtb)   (2048x1024x32)
        gemm_bf16<<<(1024 / 128) * (M_ROWS / 128), 256, 0, stream>>>(
            xdb, dtwb + (size_t)i * 1024 * 32, dtb + (size_t)i * DI, dt,
            M_ROWS, 1024, 32, 64, 32, 1);
        scan_pass1<<<dim3(DI / 256, BB, CCH), 256, 0, stream>>>(
            xc, dt, xd, A_log + (size_t)i * DI * DS, S, Qb);
        scan_pass2<<<(BB * DI * DS) / 256, 256, 0, stream>>>(
            A_log + (size_t)i * DI * DS, S, Qb);
        scan_pass3<<<dim3(DI / 256, BB, CCH), 256, 0, stream>>>(
            xc, dt, xd, xz, A_log + (size_t)i * DI * DS, Dpp + (size_t)i * DI, Qb, yb);
        // out_proj: (2048x512x1024), 128x64 tiles -> 128 blocks
        gemm_n64<<<dim3(1, M_ROWS / 128, 512 / 64), 256, 0, stream>>>(
            yb, owb + (size_t)i * 512 * 1024, o,
            1024, 1024, 512, 1024, 0);
        add_ln<<<M_ROWS, 256, 0, stream>>>(
            o, x, lng + (size_t)i * DIM, lnb + (size_t)i * DIM, xb);
    }

    gemm_bf16<<<(VOCAB / 128) * (M_ROWS / 128), 256, 0, stream>>>(
        xb, lm_wb, lm_b, out, M_ROWS, VOCAB, 512, 512, 512, 0);
}

// Round 5
// 908.337 us; speedup vs baseline: 7.7053x; 1.0518x over previous
//
#include <hip/hip_runtime.h>
#include <hip/hip_bf16.h>
#include <math.h>

#define BB 2
#define LL 1024
#define DIM 512
#define NL 6
#define DI 1024
#define DS 16
#define DC 4
#define DR 32
#define VOCAB 32000
#define M_ROWS (BB * LL)   // 2048
#define CCH 64             // scan chunks
#define CHLEN (LL / CCH)   // 16
#define KSPLIT 8           // x_proj K-split

typedef unsigned short u16;
typedef __attribute__((ext_vector_type(8))) short bf16x8;
typedef __attribute__((ext_vector_type(4))) float f32x4;

__device__ __forceinline__ u16 f2bf(float f) {
    unsigned u = __float_as_uint(f);
    u += 0x7FFF + ((u >> 16) & 1);       // round-to-nearest-even
    return (u16)(u >> 16);
}
// LDS chunk swizzle: row r, 16B-chunk c -> c ^ ((r>>1)&3)  (involution)
#define SWZ(r, c) ((c) ^ (((r) >> 1) & 3))

// ---------------------------------------------------------------------------
// fp32 -> bf16 bulk cast
// ---------------------------------------------------------------------------
__global__ __launch_bounds__(256) void cast_bf16(const float* __restrict__ in,
                                                 u16* __restrict__ out, int n8) {
    int idx = blockIdx.x * 256 + threadIdx.x;
    if (idx >= n8) return;
    float4 v0 = ((const float4*)in)[idx * 2];
    float4 v1 = ((const float4*)in)[idx * 2 + 1];
    union { u16 h[8]; int4 v; } r;
    r.h[0] = f2bf(v0.x); r.h[1] = f2bf(v0.y); r.h[2] = f2bf(v0.z); r.h[3] = f2bf(v0.w);
    r.h[4] = f2bf(v1.x); r.h[5] = f2bf(v1.y); r.h[6] = f2bf(v1.z); r.h[7] = f2bf(v1.w);
    ((int4*)out)[idx] = r.v;
}

// ---------------------------------------------------------------------------
// embed + pos  (f32 x + bf16 shadow xb)
// ---------------------------------------------------------------------------
__global__ __launch_bounds__(256) void embed_kernel(const int* __restrict__ tok,
                                                    const float* __restrict__ pos,
                                                    const float* __restrict__ emb,
                                                    float* __restrict__ x,
                                                    u16* __restrict__ xb) {
    int idx = blockIdx.x * 256 + threadIdx.x;
    int d = idx & (DIM - 1);
    int l = (idx >> 9) & (LL - 1);
    int b = idx >> 19;
    int t = tok[b * LL + l];
    float v = emb[(size_t)t * DIM + d] + pos[l * DIM + d];
    x[idx] = v;
    xb[idx] = f2bf(v);
}

// ---------------------------------------------------------------------------
// bf16 MFMA GEMM, 128x128 tile, BK=32, 3-buffer dist-2 pipelined staging.
// C[M,N](f32) = A[M,K](bf16) * W[N,K](bf16)^T (+bias).
// mode 0: C = acc (+bias);  mode 1: C = softplus(acc + bias)
// 4 global_load_lds per wave per stage -> steady vmcnt(8), tails 4, 0.
// ---------------------------------------------------------------------------
__global__ __launch_bounds__(256) void gemm_bf16(const u16* __restrict__ A,
                                                 const u16* __restrict__ W,
                                                 const float* __restrict__ bias,
                                                 float* __restrict__ C,
                                                 int M, int N, int K,
                                                 int lda, int ldw, int mode) {
    __shared__ __align__(16) u16 As[3 * 4096];
    __shared__ __align__(16) u16 Ws[3 * 4096];
    const int t = threadIdx.x;
    const int l = t & 63;
    const int w = t >> 6;
    // bijective XCD swizzle (m204), logical order: bn-major, bm fastest
    const int nwg = gridDim.x;
    const int q = nwg >> 3, r8 = nwg & 7;
    const int xcd = blockIdx.x & 7, rank = blockIdx.x >> 3;
    const int wgid = (xcd < r8 ? xcd * (q + 1) : r8 * (q + 1) + (xcd - r8) * q) + rank;
    const int Mb = M >> 7;
    const int bm = (wgid % Mb) * 128;
    const int bn = (wgid / Mb) * 128;
    const int wm = (w >> 1) * 64;
    const int wn = (w & 1) * 64;

    f32x4 acc[4][4] = {};
    const int nt = K >> 5;

    auto STAGE = [&](int bufi, int k0) {
#pragma unroll
        for (int p = 0; p < 2; ++p) {
            const int i = (p * 4 + w) * 64 + l;     // 0..511
            const int row = i >> 2;
            const int kq = SWZ(row, i & 3);
            __builtin_amdgcn_global_load_lds(
                (const __attribute__((address_space(1))) unsigned int*)
                    (A + (size_t)(bm + row) * lda + k0 + kq * 8),
                (__attribute__((address_space(3))) unsigned int*)
                    (As + bufi * 4096 + (p * 4 + w) * 512),
                16, 0, 0);
            __builtin_amdgcn_global_load_lds(
                (const __attribute__((address_space(1))) unsigned int*)
                    (W + (size_t)(bn + row) * ldw + k0 + kq * 8),
                (__attribute__((address_space(3))) unsigned int*)
                    (Ws + bufi * 4096 + (p * 4 + w) * 512),
                16, 0, 0);
        }
    };
    auto COMPUTE = [&](int bufi) {
        const u16* Ab = As + bufi * 4096;
        const u16* Wb = Ws + bufi * 4096;
#pragma unroll
        for (int mi = 0; mi < 4; ++mi) {
            const int ar = wm + mi * 16 + (l & 15);
            bf16x8 a = *(const bf16x8*)(Ab + ar * 32 + SWZ(ar, l >> 4) * 8);
#pragma unroll
            for (int ni = 0; ni < 4; ++ni) {
                const int wr = wn + ni * 16 + (l & 15);
                bf16x8 b = *(const bf16x8*)(Wb + wr * 32 + SWZ(wr, l >> 4) * 8);
                acc[mi][ni] = __builtin_amdgcn_mfma_f32_16x16x32_bf16(b, a, acc[mi][ni], 0, 0, 0);
            }
        }
    };

    STAGE(0, 0);
    if (nt == 1) {
        asm volatile("s_waitcnt vmcnt(0)\ns_barrier" ::: "memory");
        COMPUTE(0);
    } else {
        STAGE(1, 32);
        int b0 = 0;
        for (int tt = 0; tt < nt - 2; ++tt) {
            int b2 = b0 + 2; if (b2 >= 3) b2 -= 3;
            STAGE(b2, (tt + 2) << 5);
            asm volatile("s_waitcnt vmcnt(8)\ns_barrier" ::: "memory");
            COMPUTE(b0);
            asm volatile("s_waitcnt lgkmcnt(0)\ns_barrier" ::: "memory");
            ++b0; if (b0 == 3) b0 = 0;
        }
        asm volatile("s_waitcnt vmcnt(4)\ns_barrier" ::: "memory");
        COMPUTE(b0);
        asm volatile("s_waitcnt lgkmcnt(0)\ns_barrier" ::: "memory");
        ++b0; if (b0 == 3) b0 = 0;
        asm volatile("s_waitcnt vmcnt(0)\ns_barrier" ::: "memory");
        COMPUTE(b0);
    }

#pragma unroll
    for (int mi = 0; mi < 4; ++mi) {
        const int row = bm + wm + mi * 16 + (l & 15);
#pragma unroll
        for (int ni = 0; ni < 4; ++ni) {
            const int col = bn + wn + ni * 16 + ((l >> 4) << 2);
            float4 v;
            v.x = acc[mi][ni][0]; v.y = acc[mi][ni][1];
            v.z = acc[mi][ni][2]; v.w = acc[mi][ni][3];
            if (bias != nullptr) {
                float4 b4 = *(const float4*)(bias + col);
                v.x += b4.x; v.y += b4.y; v.z += b4.z; v.w += b4.w;
            }
            if (mode == 1) {
                v.x = (v.x > 20.f) ? v.x : log1pf(__expf(v.x));
                v.y = (v.y > 20.f) ? v.y : log1pf(__expf(v.y));
                v.z = (v.z > 20.f) ? v.z : log1pf(__expf(v.z));
                v.w = (v.w > 20.f) ? v.w : log1pf(__expf(v.w));
            }
            *(float4*)(C + (size_t)row * N + col) = v;
        }
    }
}

// ---------------------------------------------------------------------------
// bf16 MFMA GEMM, 128M x 64N tile, BK=32, K-split, 3-buffer dist-2 pipeline.
// 3 global_load_lds per wave per stage -> steady vmcnt(6), tails 3, 0.
// ---------------------------------------------------------------------------
__global__ __launch_bounds__(256) void gemm_n64(const u16* __restrict__ A,
                                                const u16* __restrict__ W,
                                                float* __restrict__ out,
                                                int lda, int ldw, int ldc,
                                                int KS, int pstride) {
    __shared__ __align__(16) u16 As[3 * 4096];
    __shared__ __align__(16) u16 Ws[3 * 2048];
    const int t = threadIdx.x;
    const int l = t & 63;
    const int w = t >> 6;
    const int kz = blockIdx.x;
    const int bm = blockIdx.y * 128;
    const int bnn = blockIdx.z * 64;
    const int wm = w * 32;

    f32x4 acc[2][4] = {};
    const int nt = KS >> 5;
    const int kbeg = kz * KS;

    auto STAGE = [&](int bufi, int k0) {
#pragma unroll
        for (int p = 0; p < 2; ++p) {
            const int i = p * 256 + w * 64 + l;     // 0..511
            const int row = i >> 2;
            const int kq = SWZ(row, i & 3);
            __builtin_amdgcn_global_load_lds(
                (const __attribute__((address_space(1))) unsigned int*)
                    (A + (size_t)(bm + row) * lda + k0 + kq * 8),
                (__attribute__((address_space(3))) unsigned int*)
                    (As + bufi * 4096 + (p * 256 + w * 64) * 8),
                16, 0, 0);
        }
        {
            const int i = w * 64 + l;               // 0..255
            const int row = i >> 2;
            const int kq = SWZ(row, i & 3);
            __builtin_amdgcn_global_load_lds(
                (const __attribute__((address_space(1))) unsigned int*)
                    (W + (size_t)(bnn + row) * ldw + k0 + kq * 8),
                (__attribute__((address_space(3))) unsigned int*)
                    (Ws + bufi * 2048 + (w * 64) * 8),
                16, 0, 0);
        }
    };
    auto COMPUTE = [&](int bufi) {
        const u16* Ab = As + bufi * 4096;
        const u16* Wb = Ws + bufi * 2048;
#pragma unroll
        for (int mi = 0; mi < 2; ++mi) {
            const int ar = wm + mi * 16 + (l & 15);
            bf16x8 a = *(const bf16x8*)(Ab + ar * 32 + SWZ(ar, l >> 4) * 8);
#pragma unroll
            for (int ni = 0; ni < 4; ++ni) {
                const int wr = ni * 16 + (l & 15);
                bf16x8 b = *(const bf16x8*)(Wb + wr * 32 + SWZ(wr, l >> 4) * 8);
                acc[mi][ni] = __builtin_amdgcn_mfma_f32_16x16x32_bf16(b, a, acc[mi][ni], 0, 0, 0);
            }
        }
    };

    STAGE(0, kbeg);
    if (nt == 1) {
        asm volatile("s_waitcnt vmcnt(0)\ns_barrier" ::: "memory");
        COMPUTE(0);
    } else {
        STAGE(1, kbeg + 32);
        int b0 = 0;
        for (int tt = 0; tt < nt - 2; ++tt) {
            int b2 = b0 + 2; if (b2 >= 3) b2 -= 3;
            STAGE(b2, kbeg + ((tt + 2) << 5));
            asm volatile("s_waitcnt vmcnt(6)\ns_barrier" ::: "memory");
            COMPUTE(b0);
            asm volatile("s_waitcnt lgkmcnt(0)\ns_barrier" ::: "memory");
            ++b0; if (b0 == 3) b0 = 0;
        }
        asm volatile("s_waitcnt vmcnt(3)\ns_barrier" ::: "memory");
        COMPUTE(b0);
        asm volatile("s_waitcnt lgkmcnt(0)\ns_barrier" ::: "memory");
        ++b0; if (b0 == 3) b0 = 0;
        asm volatile("s_waitcnt vmcnt(0)\ns_barrier" ::: "memory");
        COMPUTE(b0);
    }

    float* op = out + (size_t)kz * pstride;
#pragma unroll
    for (int mi = 0; mi < 2; ++mi) {
        const int row = bm + wm + mi * 16 + (l & 15);
#pragma unroll
        for (int ni = 0; ni < 4; ++ni) {
            const int col = bnn + ni * 16 + ((l >> 4) << 2);
            float4 v;
            v.x = acc[mi][ni][0]; v.y = acc[mi][ni][1];
            v.z = acc[mi][ni][2]; v.w = acc[mi][ni][3];
            *(float4*)(op + (size_t)row * ldc + col) = v;
        }
    }
}

// ---------------------------------------------------------------------------
// x_proj K-split reduce -> xd (f32) + xdb (bf16)
// ---------------------------------------------------------------------------
__global__ __launch_bounds__(256) void xdreduce(const float* __restrict__ Pf,
                                                float* __restrict__ xd,
                                                u16* __restrict__ xdb) {
    int idx = blockIdx.x * 256 + threadIdx.x;   // 2048*64
    float s = 0.f;
#pragma unroll
    for (int kz = 0; kz < KSPLIT; ++kz)
        s += Pf[(size_t)kz * (M_ROWS * 64) + idx];
    xd[idx] = s;
    xdb[idx] = f2bf(s);
}

// ---------------------------------------------------------------------------
// causal depthwise conv (DC=4) + SiLU  -> xc f32 + xcb bf16
// ---------------------------------------------------------------------------
__global__ __launch_bounds__(256) void conv_silu(const float* __restrict__ xz,
                                                 const float* __restrict__ cw,
                                                 const float* __restrict__ cb,
                                                 float* __restrict__ xc,
                                                 u16* __restrict__ xcb) {
    int idx = blockIdx.x * 256 + threadIdx.x;   // B*L*DI
    int c = idx & (DI - 1);
    int l = (idx >> 10) & (LL - 1);
    int b = idx >> 20;
    float acc = cb[c];
#pragma unroll
    for (int k = 0; k < DC; ++k) {
        int ll = l + k - (DC - 1);
        if (ll >= 0)
            acc += cw[c * DC + k] * xz[((size_t)(b * LL + ll)) * (2 * DI) + c];
    }
    float v = acc / (1.f + __expf(-acc));
    xc[idx] = v;
    xcb[idx] = f2bf(v);
}

// ---------------------------------------------------------------------------
// Chunked selective scan, pass 1
// ---------------------------------------------------------------------------
__global__ __launch_bounds__(256) void scan_pass1(const float* __restrict__ xc,
                                                  const float* __restrict__ dt,
                                                  const float* __restrict__ xdbl,
                                                  const float* __restrict__ A_log,
                                                  float* __restrict__ S,
                                                  float* __restrict__ Q) {
    const int d = blockIdx.x * 256 + threadIdx.x;
    const int b = blockIdx.y;
    const int c = blockIdx.z;
    float a[DS];
#pragma unroll
    for (int q = 0; q < 4; ++q) {
        float4 al = *(const float4*)(A_log + d * DS + q * 4);
        a[q * 4 + 0] = -__expf(al.x);
        a[q * 4 + 1] = -__expf(al.y);
        a[q * 4 + 2] = -__expf(al.z);
        a[q * 4 + 3] = -__expf(al.w);
    }
    float Qr[DS];
#pragma unroll
    for (int n = 0; n < DS; ++n) Qr[n] = 0.f;
    float Ssum = 0.f;

    const int l0 = c * CHLEN;
    const float* dtp = dt + ((size_t)b * LL + l0) * DI + d;
    const float* up  = xc + ((size_t)b * LL + l0) * DI + d;
    const float* xdp = xdbl + ((size_t)b * LL + l0) * 64 + DR;

    for (int l = 0; l < CHLEN; ++l) {
        float dtv = dtp[(size_t)l * DI];
        float uv  = up[(size_t)l * DI];
        float wv = dtv * uv;
        Ssum += dtv;
#pragma unroll
        for (int q = 0; q < 4; ++q) {
            float4 Bv = *(const float4*)(xdp + l * 64 + q * 4);
            float dA0 = __expf(dtv * a[q * 4 + 0]);
            float dA1 = __expf(dtv * a[q * 4 + 1]);
            float dA2 = __expf(dtv * a[q * 4 + 2]);
            float dA3 = __expf(dtv * a[q * 4 + 3]);
            Qr[q * 4 + 0] = dA0 * Qr[q * 4 + 0] + wv * Bv.x;
            Qr[q * 4 + 1] = dA1 * Qr[q * 4 + 1] + wv * Bv.y;
            Qr[q * 4 + 2] = dA2 * Qr[q * 4 + 2] + wv * Bv.z;
            Qr[q * 4 + 3] = dA3 * Qr[q * 4 + 3] + wv * Bv.w;
        }
    }
    S[((size_t)b * CCH + c) * DI + d] = Ssum;
    float* Qp = Q + (((size_t)b * CCH + c) * DI + d) * DS;
#pragma unroll
    for (int q = 0; q < 4; ++q) {
        float4 o;
        o.x = Qr[q * 4 + 0]; o.y = Qr[q * 4 + 1];
        o.z = Qr[q * 4 + 2]; o.w = Qr[q * 4 + 3];
        *(float4*)(Qp + q * 4) = o;
    }
}

// ---------------------------------------------------------------------------
// Pass 2: sequential combine over chunks
// ---------------------------------------------------------------------------
__global__ __launch_bounds__(256) void scan_pass2(const float* __restrict__ A_log,
                                                  const float* __restrict__ S,
                                                  float* __restrict__ Q) {
    const int idx = blockIdx.x * 256 + threadIdx.x;
    const int b = idx >> 14;
    const int dn = idx & 16383;
    const int d = dn >> 4;
    const float a = -__expf(A_log[dn]);
    float h = 0.f;
    for (int c = 0; c < CCH; ++c) {
        const size_t soff = ((size_t)b * CCH + c) * DI + d;
        const size_t qoff = ((size_t)b * CCH + c) * (size_t)(DI * DS) + dn;
        float P = __expf(a * S[soff]);
        float qv = Q[qoff];
        Q[qoff] = h;
        h = P * h + qv;
    }
}

// ---------------------------------------------------------------------------
// Pass 3: per-chunk recurrence; gated bf16 output
// ---------------------------------------------------------------------------
__global__ __launch_bounds__(256) void scan_pass3(const float* __restrict__ xc,
                                                  const float* __restrict__ dt,
                                                  const float* __restrict__ xdbl,
                                                  const float* __restrict__ xz,
                                                  const float* __restrict__ A_log,
                                                  const float* __restrict__ Dpp,
                                                  const float* __restrict__ Q,
                                                  u16* __restrict__ y) {
    const int d = blockIdx.x * 256 + threadIdx.x;
    const int b = blockIdx.y;
    const int c = blockIdx.z;
    float a[DS];
#pragma unroll
    for (int q = 0; q < 4; ++q) {
        float4 al = *(const float4*)(A_log + d * DS + q * 4);
        a[q * 4 + 0] = -__expf(al.x);
        a[q * 4 + 1] = -__expf(al.y);
        a[q * 4 + 2] = -__expf(al.z);
        a[q * 4 + 3] = -__expf(al.w);
    }
    float h[DS];
    const float* Qp = Q + (((size_t)b * CCH + c) * DI + d) * DS;
#pragma unroll
    for (int q = 0; q < 4; ++q) {
        float4 hv = *(const float4*)(Qp + q * 4);
        h[q * 4 + 0] = hv.x; h[q * 4 + 1] = hv.y;
        h[q * 4 + 2] = hv.z; h[q * 4 + 3] = hv.w;
    }
    const float dp = Dpp[d];

    const int l0 = c * CHLEN;
    const float* dtp = dt + ((size_t)b * LL + l0) * DI + d;
    const float* up  = xc + ((size_t)b * LL + l0) * DI + d;
    const float* xdp = xdbl + ((size_t)b * LL + l0) * 64 + DR;
    const float* zp  = xz + ((size_t)b * LL + l0) * (2 * DI) + DI + d;
    u16* yp = y + ((size_t)b * LL + l0) * DI + d;

    for (int l = 0; l < CHLEN; ++l) {
        float dtv = dtp[(size_t)l * DI];
        float uv  = up[(size_t)l * DI];
        float wv = dtv * uv;
        float p = 0.f;
#pragma unroll
        for (int q = 0; q < 4; ++q) {
            float4 Bv = *(const float4*)(xdp + l * 64 + q * 4);
            float4 Cv = *(const float4*)(xdp + l * 64 + 16 + q * 4);
            float dA0 = __expf(dtv * a[q * 4 + 0]);
            float dA1 = __expf(dtv * a[q * 4 + 1]);
            float dA2 = __expf(dtv * a[q * 4 + 2]);
            float dA3 = __expf(dtv * a[q * 4 + 3]);
            h[q * 4 + 0] = dA0 * h[q * 4 + 0] + wv * Bv.x;
            h[q * 4 + 1] = dA1 * h[q * 4 + 1] + wv * Bv.y;
            h[q * 4 + 2] = dA2 * h[q * 4 + 2] + wv * Bv.z;
            h[q * 4 + 3] = dA3 * h[q * 4 + 3] + wv * Bv.w;
            p += h[q * 4 + 0] * Cv.x + h[q * 4 + 1] * Cv.y +
                 h[q * 4 + 2] * Cv.z + h[q * 4 + 3] * Cv.w;
        }
        float zv = zp[(size_t)l * (2 * DI)];
        float g = zv / (1.f + __expf(-zv));
        yp[(size_t)l * DI] = f2bf((p + uv * dp) * g);
    }
}

// ---------------------------------------------------------------------------
// x = LayerNorm(x + o) * g + b   (+ bf16 shadow)
// ---------------------------------------------------------------------------
__global__ __launch_bounds__(256) void add_ln(const float* __restrict__ o,
                                              float* __restrict__ x,
                                              const float* __restrict__ g,
                                              const float* __restrict__ b,
                                              u16* __restrict__ xb) {
    int m = blockIdx.x;
    int t = threadIdx.x;
    const float* xr = x + (size_t)m * DIM;
    const float* orr = o + (size_t)m * DIM;
    float v0 = xr[t] + orr[t];
    float v1 = xr[t + 256] + orr[t + 256];
    float s = v0 + v1;
    float ss = v0 * v0 + v1 * v1;
#pragma unroll
    for (int off = 32; off > 0; off >>= 1) {
        s += __shfl_down(s, off, 64);
        ss += __shfl_down(ss, off, 64);
    }
    __shared__ float sb[4], ssb[4];
    int w = t >> 6;
    if ((t & 63) == 0) { sb[w] = s; ssb[w] = ss; }
    __syncthreads();
    float stot = sb[0] + sb[1] + sb[2] + sb[3];
    float sstot = ssb[0] + ssb[1] + ssb[2] + ssb[3];
    float mean = stot * (1.f / DIM);
    float var = sstot * (1.f / DIM) - mean * mean;
    float rs = rsqrtf(var + 1e-5f);
    float* xw = x + (size_t)m * DIM;
    float o0 = (v0 - mean) * rs * g[t] + b[t];
    float o1 = (v1 - mean) * rs * g[t + 256] + b[t + 256];
    xw[t] = o0;
    xw[t + 256] = o1;
    xb[(size_t)m * DIM + t] = f2bf(o0);
    xb[(size_t)m * DIM + t + 256] = f2bf(o1);
}

// ---------------------------------------------------------------------------
extern "C" void kernel_launch(void* const* d_in, const int* in_sizes, int n_in,
                              void* d_out, int out_size, void* d_ws, size_t ws_size,
                              hipStream_t stream) {
    const int*   tokens = (const int*)d_in[0];
    const float* pos    = (const float*)d_in[1];
    const float* emb    = (const float*)d_in[2];
    const float* lm_w   = (const float*)d_in[3];
    const float* lm_b   = (const float*)d_in[4];
    const float* in_w   = (const float*)d_in[5];
    const float* cw     = (const float*)d_in[6];
    const float* cb     = (const float*)d_in[7];
    const float* xpw    = (const float*)d_in[8];
    const float* dtw    = (const float*)d_in[9];
    const float* dtb    = (const float*)d_in[10];
    const float* A_log  = (const float*)d_in[11];
    const float* Dpp    = (const float*)d_in[12];
    const float* ow     = (const float*)d_in[13];
    const float* lng    = (const float*)d_in[14];
    const float* lnb    = (const float*)d_in[15];
    float* out = (float*)d_out;

    float* ws = (float*)d_ws;
    float* x    = ws;                   // 1048576
    float* xz   = x + 1048576;          // 4194304
    float* xc   = xz + 4194304;         // 2097152
    float* xd   = xc + 2097152;         // 131072
    float* dt   = xd + 131072;          // 2097152
    float* o    = dt + 2097152;         // 1048576
    float* S    = o + 1048576;          // B*CCH*DI = 131072
    float* Qb   = S + 131072;           // B*CCH*DI*DS = 2097152
    float* Pf   = Qb + 2097152;         // KSPLIT*2048*64 = 1048576
    u16* xb     = (u16*)(Pf + 1048576); // 1048576
    u16* yb     = xb + 1048576;         // 2097152
    u16* xcb    = yb + 2097152;         // 2097152
    u16* xdb    = xcb + 2097152;        // 131072
    u16* lm_wb  = xdb + 131072;         // 16384000
    u16* in_wb  = lm_wb + 16384000;     // 6291456
    u16* owb    = in_wb + 6291456;      // 3145728
    u16* xpwb   = owb + 3145728;        // 393216
    u16* dtwb   = xpwb + 393216;        // 196608

    cast_bf16<<<16384000 / 8 / 256, 256, 0, stream>>>(lm_w, lm_wb, 16384000 / 8);
    cast_bf16<<<6291456 / 8 / 256, 256, 0, stream>>>(in_w, in_wb, 6291456 / 8);
    cast_bf16<<<3145728 / 8 / 256, 256, 0, stream>>>(ow, owb, 3145728 / 8);
    cast_bf16<<<393216 / 8 / 256, 256, 0, stream>>>(xpw, xpwb, 393216 / 8);
    cast_bf16<<<196608 / 8 / 256, 256, 0, stream>>>(dtw, dtwb, 196608 / 8);

    embed_kernel<<<M_ROWS * DIM / 256, 256, 0, stream>>>(tokens, pos, emb, x, xb);

    for (int i = 0; i < NL; ++i) {
        // in_proj: (2048x2048x512)
        gemm_bf16<<<(2048 / 128) * (M_ROWS / 128), 256, 0, stream>>>(
            xb, in_wb + (size_t)i * 2048 * 512, nullptr, xz,
            M_ROWS, 2048, 512, 512, 512, 0);
        conv_silu<<<M_ROWS * DI / 256, 256, 0, stream>>>(
            xz, cw + (size_t)i * DI * DC, cb + (size_t)i * DI, xc, xcb);
        // x_proj: (2048x64x1024), K-split 8 -> Pf
        gemm_n64<<<dim3(KSPLIT, M_ROWS / 128, 1), 256, 0, stream>>>(
            xcb, xpwb + (size_t)i * 64 * 1024, Pf,
            1024, 1024, 64, 1024 / KSPLIT, M_ROWS * 64);
        xdreduce<<<M_ROWS * 64 / 256, 256, 0, stream>>>(Pf, xd, xdb);
        // dt: softplus(xd[:, :32] @ dtw^T + dtb)   (2048x1024x32)
        gemm_bf16<<<(1024 / 128) * (M_ROWS / 128), 256, 0, stream>>>(
            xdb, dtwb + (size_t)i * 1024 * 32, dtb + (size_t)i * DI, dt,
            M_ROWS, 1024, 32, 64, 32, 1);
        scan_pass1<<<dim3(DI / 256, BB, CCH), 256, 0, stream>>>(
            xc, dt, xd, A_log + (size_t)i * DI * DS, S, Qb);
        scan_pass2<<<(BB * DI * DS) / 256, 256, 0, stream>>>(
            A_log + (size_t)i * DI * DS, S, Qb);
        scan_pass3<<<dim3(DI / 256, BB, CCH), 256, 0, stream>>>(
            xc, dt, xd, xz, A_log + (size_t)i * DI * DS, Dpp + (size_t)i * DI, Qb, yb);
        // out_proj: (2048x512x1024)
        gemm_n64<<<dim3(1, M_ROWS / 128, 512 / 64), 256, 0, stream>>>(
            yb, owb + (size_t)i * 512 * 1024, o,
            1024, 1024, 512, 1024, 0);
        add_ln<<<M_ROWS, 256, 0, stream>>>(
            o, x, lng + (size_t)i * DIM, lnb + (size_t)i * DIM, xb);
    }

    gemm_bf16<<<(VOCAB / 128) * (M_ROWS / 128), 256, 0, stream>>>(
        xb, lm_wb, lm_b, out, M_ROWS, VOCAB, 512, 512, 512, 0);
}